// Round 2
// baseline (1873.491 us; speedup 1.0000x reference)
//
#include <hip/hip_runtime.h>

// Problem constants (B=4, C=64, H=W=192)
#define HH 192
#define WID 192
#define HW (HH*WID)          // 36864
#define CB 64
#define BB 4
#define NPOS (BB*HW)         // 147456

typedef __attribute__((ext_vector_type(8))) _Float16 half8v;
typedef __attribute__((ext_vector_type(4))) _Float16 half4v;
typedef __attribute__((ext_vector_type(8))) unsigned short ushort8;
typedef __attribute__((ext_vector_type(4))) float f32x4;

static __device__ inline half8v splat8(_Float16 x) {
    half8v v = {x, x, x, x, x, x, x, x};
    return v;
}

// x tensors: CHANNEL-PLANE fp16 layout x[b][plane=c>>3][hw][8ch] (16B/pos/plane).
// Offsets: TAP-MAJOR float2 planes off[k][global_pos][2] (NPOS float2 per plane).

// ---------------------------------------------------------------------------
// K1: LayerNorm over C + 1x1 conv C->2C; outputs x1/x2 in plane-fp16 layout.
// ---------------------------------------------------------------------------
__global__ __launch_bounds__(256) void k_ln_conv_in(
    const float* __restrict__ x, const float* __restrict__ g, const float* __restrict__ be,
    const float* __restrict__ w_in, const float* __restrict__ b_in,
    _Float16* __restrict__ x1, _Float16* __restrict__ x2)
{
    int p  = blockIdx.x * 256 + threadIdx.x;     // [0, NPOS)
    int b  = p / HW;
    int hw = p % HW;
    const float* xp = x + (size_t)b * CB * HW + hw;

    float v[64];
    float sum = 0.f, sumsq = 0.f;
#pragma unroll
    for (int c = 0; c < 64; c++) {
        float t = xp[c * HW];
        v[c] = t; sum += t; sumsq += t * t;
    }
    float mu  = sum * (1.f / 64.f);
    float var = sumsq * (1.f / 64.f) - mu * mu;
    float inv = rsqrtf(var + 1e-5f);
#pragma unroll
    for (int c = 0; c < 64; c++) v[c] = (v[c] - mu) * inv * g[c] + be[c];

    _Float16* o1 = x1 + (size_t)b * HW * 64 + (size_t)hw * 8;
    _Float16* o2 = x2 + (size_t)b * HW * 64 + (size_t)hw * 8;
    for (int pl = 0; pl < 8; pl++) {            // pl = channel plane (8 ch)
        half8v r1, r2;
#pragma unroll
        for (int j = 0; j < 8; j++) {
            int o = pl * 8 + j;
            float a1 = b_in[o];
            float a2 = b_in[o + 64];
#pragma unroll
            for (int c = 0; c < 64; c++) {
                a1 += v[c] * w_in[o * 64 + c];
                a2 += v[c] * w_in[(o + 64) * 64 + c];
            }
            r1[j] = (_Float16)a1;
            r2[j] = (_Float16)a2;
        }
        *(half8v*)&o1[(size_t)pl * HW * 8] = r1;
        *(half8v*)&o2[(size_t)pl * HW * 8] = r2;
    }
}

// ---------------------------------------------------------------------------
// Weight prep: w[o][c][ki][kj] fp32 (OIHW) -> wt[k][o][c] fp16, o padded to OP.
// ---------------------------------------------------------------------------
template<int KK, int CO, int OP>
__global__ void k_wth(const float* __restrict__ w, _Float16* __restrict__ wt)
{
    int idx = blockIdx.x * 256 + threadIdx.x;
    constexpr int TOT = KK * OP * 64;
    if (idx >= TOT) return;
    int k = idx / (OP * 64);
    int r = idx % (OP * 64);
    int o = r / 64;
    int c = r % 64;
    float v = (o < CO) ? w[((size_t)o * 64 + c) * KK + k] : 0.f;
    wt[idx] = (_Float16)v;
}

// ---------------------------------------------------------------------------
// Corner-register set for one in-flight deform tile-tap.
// ---------------------------------------------------------------------------
struct CornerRegs {
    half8v r[8];             // {00lo,00hi,01lo,01hi,10lo,10hi,11lo,11hi}
    float w00, w01, w10, w11;
};

static __device__ inline void d_issue(const _Float16* __restrict__ xq0,
                                      const _Float16* __restrict__ xq1,
                                      int y, int xg, int ki, int kj, int PAD,
                                      float2 off, CornerRegs& C)
{
    float py = (float)(y + ki - PAD) + off.x;
    float px = (float)(xg + kj - PAD) + off.y;
    float fy = floorf(py), fx = floorf(px);
    float wy = py - fy, wx = px - fx;
    int iy0 = (int)fy, ix0 = (int)fx;
    int iy1 = iy0 + 1, ix1 = ix0 + 1;
    float m00 = (iy0 >= 0 && iy0 < HH && ix0 >= 0 && ix0 < WID) ? 1.f : 0.f;
    float m01 = (iy0 >= 0 && iy0 < HH && ix1 >= 0 && ix1 < WID) ? 1.f : 0.f;
    float m10 = (iy1 >= 0 && iy1 < HH && ix0 >= 0 && ix0 < WID) ? 1.f : 0.f;
    float m11 = (iy1 >= 0 && iy1 < HH && ix1 >= 0 && ix1 < WID) ? 1.f : 0.f;
    int cy0 = min(max(iy0, 0), HH - 1), cy1 = min(max(iy1, 0), HH - 1);
    int cx0 = min(max(ix0, 0), WID - 1), cx1 = min(max(ix1, 0), WID - 1);
    size_t i00 = (size_t)(cy0 * WID + cx0) * 8, i01 = (size_t)(cy0 * WID + cx1) * 8;
    size_t i10 = (size_t)(cy1 * WID + cx0) * 8, i11 = (size_t)(cy1 * WID + cx1) * 8;
    C.r[0] = *(const half8v*)(xq0 + i00);  C.r[1] = *(const half8v*)(xq1 + i00);
    C.r[2] = *(const half8v*)(xq0 + i01);  C.r[3] = *(const half8v*)(xq1 + i01);
    C.r[4] = *(const half8v*)(xq0 + i10);  C.r[5] = *(const half8v*)(xq1 + i10);
    C.r[6] = *(const half8v*)(xq0 + i11);  C.r[7] = *(const half8v*)(xq1 + i11);
    C.w00 = (1.f - wy) * (1.f - wx) * m00;
    C.w01 = (1.f - wy) * wx * m01;
    C.w10 = wy * (1.f - wx) * m10;
    C.w11 = wy * wx * m11;
}

// packed fp16 bilinear combine: ~8 v_pk_fma_f16 per half8v
static __device__ inline void d_combine(const CornerRegs& C, half8v& f0, half8v& f1)
{
    half8v w00v = splat8((_Float16)C.w00);
    half8v w01v = splat8((_Float16)C.w01);
    half8v w10v = splat8((_Float16)C.w10);
    half8v w11v = splat8((_Float16)C.w11);
    f0 = C.r[0] * w00v + C.r[2] * w01v + C.r[4] * w10v + C.r[6] * w11v;
    f1 = C.r[1] * w00v + C.r[3] * w01v + C.r[5] * w10v + C.r[7] * w11v;
}

static __device__ inline void d_issue_conv(const _Float16* __restrict__ xq0,
                                           const _Float16* __restrict__ xq1,
                                           int y, int xg, int ki, int kj, int PAD,
                                           half8v& f0, half8v& f1)
{
    int gy = y + ki - PAD;
    int gx = xg + kj - PAD;
    bool ok = (gy >= 0 && gy < HH && gx >= 0 && gx < WID);
    if (ok) {
        size_t i = (size_t)(gy * WID + gx) * 8;
        f0 = *(const half8v*)(xq0 + i);
        f1 = *(const half8v*)(xq1 + i);
    } else {
        f0 = splat8((_Float16)0.f); f1 = splat8((_Float16)0.f);
    }
}

// ---------------------------------------------------------------------------
// Barrier-free wave-local MFMA conv, plane fp16 layout, NT pos-tiles per wave.
// (kept for the DEFORM=false offset convs; deform path uses k_sconv)
// ---------------------------------------------------------------------------
template<int K, int PAD, int NOT, int CO, int NT, bool DEFORM>
__global__ __launch_bounds__(256) void k_mconv(
    const _Float16* __restrict__ xin, const float* __restrict__ offp,
    const _Float16* __restrict__ wtb, const float* __restrict__ bias,
    void* __restrict__ outv)
{
    constexpr int KK = K * K;
    constexpr int OP = NOT * 16;
    constexpr int KTAP = CO / 2;                 // tap count of the offset consumer
    constexpr int BP = 64 * NT;                  // positions per block

    int p0  = blockIdx.x * BP;
    int b   = p0 / HW;
    int hwb = p0 % HW;

    int t    = threadIdx.x;
    int lane = t & 63;
    int wave = t >> 6;
    int p    = lane & 15;
    int q    = lane >> 4;
    int wlane = p * 8 + q;            // A-frag offset (half8 units)

    // per-tile coordinates
    int yt[NT], xt[NT], gp[NT];
#pragma unroll
    for (int j = 0; j < NT; j++) {
        int hwt = hwb + (wave * NT + j) * 16;
        yt[j] = hwt / WID;
        xt[j] = hwt % WID + p;
        gp[j] = p0 + (wave * NT + j) * 16 + p;
    }

    f32x4 acc[NT][NOT];
#pragma unroll
    for (int j = 0; j < NT; j++)
#pragma unroll
        for (int ot = 0; ot < NOT; ot++) acc[j][ot] = (f32x4){0.f, 0.f, 0.f, 0.f};

    const _Float16* xb  = xin + (size_t)b * HW * 64;
    const _Float16* xq0 = xb + (size_t)q * HW * 8;          // chunk-0 plane
    const _Float16* xq1 = xb + (size_t)(q + 4) * HW * 8;    // chunk-1 plane
    const half8v* wbase = (const half8v*)wtb;

    const float2* offj[NT];
    float2 offc[NT], offn[NT];
    if (DEFORM) {
#pragma unroll
        for (int j = 0; j < NT; j++) {
            offj[j] = (const float2*)offp + gp[j];
            offc[j] = offj[j][0];
        }
    }

    int ki = 0, kj = 0;
    for (int k = 0; k < KK; k++) {
        if (DEFORM) {
#pragma unroll
            for (int j = 0; j < NT; j++)
                offn[j] = offj[j][(size_t)(k + 1) * NPOS];
        }
        const half8v* wp = wbase + (size_t)k * OP * 8;
        half8v aw0[NOT], aw1[NOT];
#pragma unroll
        for (int ot = 0; ot < NOT; ot++) {
            aw0[ot] = wp[ot * 128 + wlane];
            aw1[ot] = wp[ot * 128 + wlane + 4];
        }

        if (DEFORM) {
            CornerRegs CC[2];
            d_issue(xq0, xq1, yt[0], xt[0], ki, kj, PAD, offc[0], CC[0]);
#pragma unroll
            for (int j = 0; j < NT; j++) {
                if (j + 1 < NT)
                    d_issue(xq0, xq1, yt[j + 1], xt[j + 1], ki, kj, PAD, offc[j + 1], CC[(j + 1) & 1]);
                half8v f0, f1;
                d_combine(CC[j & 1], f0, f1);
#pragma unroll
                for (int ot = 0; ot < NOT; ot++)
                    acc[j][ot] = __builtin_amdgcn_mfma_f32_16x16x32_f16(aw0[ot], f0, acc[j][ot], 0, 0, 0);
#pragma unroll
                for (int ot = 0; ot < NOT; ot++)
                    acc[j][ot] = __builtin_amdgcn_mfma_f32_16x16x32_f16(aw1[ot], f1, acc[j][ot], 0, 0, 0);
            }
#pragma unroll
            for (int j = 0; j < NT; j++) offc[j] = offn[j];
        } else {
            half8v f0[NT], f1[NT];
#pragma unroll
            for (int j = 0; j < NT; j++)
                d_issue_conv(xq0, xq1, yt[j], xt[j], ki, kj, PAD, f0[j], f1[j]);
#pragma unroll
            for (int j = 0; j < NT; j++) {
#pragma unroll
                for (int ot = 0; ot < NOT; ot++)
                    acc[j][ot] = __builtin_amdgcn_mfma_f32_16x16x32_f16(aw0[ot], f0[j], acc[j][ot], 0, 0, 0);
#pragma unroll
                for (int ot = 0; ot < NOT; ot++)
                    acc[j][ot] = __builtin_amdgcn_mfma_f32_16x16x32_f16(aw1[ot], f1[j], acc[j][ot], 0, 0, 0);
            }
        }

        kj++;
        if (kj == K) { kj = 0; ki++; }
    }

    // ---- epilogue: D reg i -> o = ot*16 + q*4 + i, pos = gp[j] ----
    if (DEFORM) {
        _Float16* outp = (_Float16*)outv;
#pragma unroll
        for (int j = 0; j < NT; j++) {
            int hwp = hwb + (wave * NT + j) * 16 + p;
#pragma unroll
            for (int ot = 0; ot < NOT; ot++) {
                int ob = ot * 16 + q * 4;
                int plane = ob >> 3;
                int intra = ob & 7;
                float4 bb = *(const float4*)&bias[ob];
                half4v r;
                r[0] = (_Float16)(acc[j][ot][0] + bb.x);
                r[1] = (_Float16)(acc[j][ot][1] + bb.y);
                r[2] = (_Float16)(acc[j][ot][2] + bb.z);
                r[3] = (_Float16)(acc[j][ot][3] + bb.w);
                *(half4v*)&outp[(size_t)b * HW * 64 + (size_t)plane * HW * 8
                                + (size_t)hwp * 8 + intra] = r;
            }
        }
    } else {
        float* outf = (float*)outv;   // tap-major float2 planes
#pragma unroll
        for (int j = 0; j < NT; j++) {
#pragma unroll
            for (int ot = 0; ot < NOT; ot++) {
                int ob = ot * 16 + q * 4;     // channels ob..ob+3 = taps ob/2, ob/2+1
                int t0 = ob >> 1;
                if (t0 < KTAP) {
                    float2 r; r.x = acc[j][ot][0] + bias[ob];     r.y = acc[j][ot][1] + bias[ob + 1];
                    *(float2*)&outf[((size_t)t0 * NPOS + gp[j]) * 2] = r;
                }
                if (t0 + 1 < KTAP) {
                    float2 r; r.x = acc[j][ot][2] + bias[ob + 2]; r.y = acc[j][ot][3] + bias[ob + 3];
                    *(float2*)&outf[((size_t)(t0 + 1) * NPOS + gp[j]) * 2] = r;
                }
            }
        }
    }
}

// ---------------------------------------------------------------------------
// k_sconv v2: LDS-staged deform conv. Block = 16x16 positions, 512 threads
// (8 waves x NT=2 tiles of 2rows x 8cols). Staged region (16+2H)^2 pixels,
// 128 B/pixel: 72 KB (K=7) / 60.5 KB (K=5) / 50 KB (K=3) -> 2-3 blocks/CU
// = 16-24 waves/CU (vs 12 in v1). Halo redundancy 2.25x (vs 3x).
// Swizzle: 16B slot = plane ^ ((3*row + col) & 7) -- row-aware, so the
// per-lane offset jitter (iy0/ix0 +-1) no longer aliases slots: a +-1 row
// step moves the slot by 3, col step by 1 (3*dr+dc != 0 mod 8 for the
// jitter range). v1's col-only swizzle gave 13.9M conflict cycles.
// Per-lane global fallback when a corner exits the halo (|off|>=1).
// Numerics identical to v1 (same fp16 samples/combine/MFMA order).
// ---------------------------------------------------------------------------
template<int K, int PAD, int HALO>
__global__ __launch_bounds__(512, 4) void k_sconv(
    const _Float16* __restrict__ xin, const float* __restrict__ offp,
    const _Float16* __restrict__ wtb, const float* __restrict__ bias,
    _Float16* __restrict__ outp)
{
    constexpr int KK = K * K;
    constexpr int RB = 16 + 2 * HALO;     // staged rows
    constexpr int WB = 16 + 2 * HALO;     // staged cols
    constexpr int NT = 2;

    __shared__ half8v sm[RB * WB * 8];    // 16B slot per (pixel, plane)

    int bi  = blockIdx.x;
    int b   = bi / 144;                   // 144 = 12 row-tiles * 12 col-tiles
    int tt  = bi % 144;
    int by0 = (tt / 12) * 16;
    int bx0 = (tt % 12) * 16;
    int ry0 = by0 - HALO;
    int rx0 = bx0 - HALO;

    const _Float16* xb  = xin + (size_t)b * HW * 64;

    // ---- stage tile + halo (edge-clamped rows/cols) ----
    constexpr int CH = RB * WB * 8;       // 16B chunks
    for (int i = threadIdx.x; i < CH; i += 512) {
        int cc = i % WB;
        int rp = i / WB;
        int pl = rp & 7;
        int r  = rp >> 3;
        int yr = min(max(ry0 + r,  0), HH - 1);
        int xc = min(max(rx0 + cc, 0), WID - 1);
        half8v ch = *(const half8v*)(xb + ((size_t)pl * HW + (size_t)(yr * WID + xc)) * 8);
        sm[(r * WB + cc) * 8 + (pl ^ ((3 * r + cc) & 7))] = ch;
    }
    __syncthreads();

    int t    = threadIdx.x;
    int lane = t & 63;
    int wave = t >> 6;                    // 0..7
    int p    = lane & 15;
    int q    = lane >> 4;
    int wlane = p * 8 + q;
    int dr   = p >> 3;                    // tile-local row (0..1)
    int dc   = p & 7;                     // tile-local col (0..7)

    const _Float16* xq0 = xb + (size_t)q * HW * 8;        // fallback planes
    const _Float16* xq1 = xb + (size_t)(q + 4) * HW * 8;
    const half8v* wbase = (const half8v*)wtb;

    int yt = by0 + wave * 2 + dr;         // same row pair for both tiles
    int xt[NT], gp[NT];
#pragma unroll
    for (int j = 0; j < NT; j++) {
        xt[j] = bx0 + j * 8 + dc;
        gp[j] = b * HW + yt * WID + xt[j];
    }

    f32x4 acc[NT][4];
#pragma unroll
    for (int j = 0; j < NT; j++)
#pragma unroll
        for (int ot = 0; ot < 4; ot++) acc[j][ot] = (f32x4){0.f, 0.f, 0.f, 0.f};

    const float2* offj[NT];
    float2 offc[NT], offn[NT];
#pragma unroll
    for (int j = 0; j < NT; j++) {
        offj[j] = (const float2*)offp + gp[j];
        offc[j] = offj[j][0];
    }

    // corner fetch for one tile-tap (fast: swizzled LDS; rare fallback: global)
    auto fetch = [&](int xg, int ki, int kj, float2 off, CornerRegs& C) {
        float py = (float)(yt + ki - PAD) + off.x;
        float px = (float)(xg + kj - PAD) + off.y;
        float fy = floorf(py), fx = floorf(px);
        float wy = py - fy, wx = px - fx;
        int iy0 = (int)fy, ix0 = (int)fx;
        int iy1 = iy0 + 1, ix1 = ix0 + 1;
        float m00 = (iy0 >= 0 && iy0 < HH && ix0 >= 0 && ix0 < WID) ? 1.f : 0.f;
        float m01 = (iy0 >= 0 && iy0 < HH && ix1 >= 0 && ix1 < WID) ? 1.f : 0.f;
        float m10 = (iy1 >= 0 && iy1 < HH && ix0 >= 0 && ix0 < WID) ? 1.f : 0.f;
        float m11 = (iy1 >= 0 && iy1 < HH && ix1 >= 0 && ix1 < WID) ? 1.f : 0.f;
        C.w00 = (1.f - wy) * (1.f - wx) * m00;
        C.w01 = (1.f - wy) * wx * m01;
        C.w10 = wy * (1.f - wx) * m10;
        C.w11 = wy * wx * m11;
        bool fast = (iy0 >= ry0) && (iy1 <= ry0 + RB - 1) &&
                    (ix0 >= rx0) && (ix1 <= rx0 + WB - 1);
        if (__builtin_expect(fast, 1)) {
            int r0 = iy0 - ry0, c0 = ix0 - rx0;
            int p00 = r0 * WB + c0;
            int m0 = (3 * r0 + c0) & 7;          // slot keys: +1 (col), +3 (row)
            int m1 = (m0 + 1) & 7;
            int m2 = (m0 + 3) & 7;
            int m3 = (m0 + 4) & 7;
            C.r[0] = sm[p00 * 8            + ( q      ^ m0)];
            C.r[1] = sm[p00 * 8            + ((q + 4) ^ m0)];
            C.r[2] = sm[(p00 + 1) * 8      + ( q      ^ m1)];
            C.r[3] = sm[(p00 + 1) * 8      + ((q + 4) ^ m1)];
            C.r[4] = sm[(p00 + WB) * 8     + ( q      ^ m2)];
            C.r[5] = sm[(p00 + WB) * 8     + ((q + 4) ^ m2)];
            C.r[6] = sm[(p00 + WB + 1) * 8 + ( q      ^ m3)];
            C.r[7] = sm[(p00 + WB + 1) * 8 + ((q + 4) ^ m3)];
        } else {
            int cy0 = min(max(iy0, 0), HH - 1), cy1 = min(max(iy1, 0), HH - 1);
            int cx0 = min(max(ix0, 0), WID - 1), cx1 = min(max(ix1, 0), WID - 1);
            size_t i00 = (size_t)(cy0 * WID + cx0) * 8, i01 = (size_t)(cy0 * WID + cx1) * 8;
            size_t i10 = (size_t)(cy1 * WID + cx0) * 8, i11 = (size_t)(cy1 * WID + cx1) * 8;
            C.r[0] = *(const half8v*)(xq0 + i00);  C.r[1] = *(const half8v*)(xq1 + i00);
            C.r[2] = *(const half8v*)(xq0 + i01);  C.r[3] = *(const half8v*)(xq1 + i01);
            C.r[4] = *(const half8v*)(xq0 + i10);  C.r[5] = *(const half8v*)(xq1 + i10);
            C.r[6] = *(const half8v*)(xq0 + i11);  C.r[7] = *(const half8v*)(xq1 + i11);
        }
    };

    int ki = 0, kj = 0;
    for (int k = 0; k < KK; k++) {
#pragma unroll
        for (int j = 0; j < NT; j++)
            offn[j] = offj[j][(size_t)(k + 1) * NPOS];

        const half8v* wp = wbase + (size_t)k * 64 * 8;   // OP = 64
        half8v aw0[4], aw1[4];
#pragma unroll
        for (int ot = 0; ot < 4; ot++) {
            aw0[ot] = wp[ot * 128 + wlane];
            aw1[ot] = wp[ot * 128 + wlane + 4];
        }

        CornerRegs CC[2];
        fetch(xt[0], ki, kj, offc[0], CC[0]);
#pragma unroll
        for (int j = 0; j < NT; j++) {
            if (j + 1 < NT)
                fetch(xt[j + 1], ki, kj, offc[j + 1], CC[(j + 1) & 1]);
            half8v f0, f1;
            d_combine(CC[j & 1], f0, f1);
#pragma unroll
            for (int ot = 0; ot < 4; ot++)
                acc[j][ot] = __builtin_amdgcn_mfma_f32_16x16x32_f16(aw0[ot], f0, acc[j][ot], 0, 0, 0);
#pragma unroll
            for (int ot = 0; ot < 4; ot++)
                acc[j][ot] = __builtin_amdgcn_mfma_f32_16x16x32_f16(aw1[ot], f1, acc[j][ot], 0, 0, 0);
        }
#pragma unroll
        for (int j = 0; j < NT; j++) offc[j] = offn[j];

        kj++;
        if (kj == K) { kj = 0; ki++; }
    }

    // ---- epilogue: D reg i -> o = ot*16 + q*4 + i, pos = (yt, xt[j]) ----
#pragma unroll
    for (int j = 0; j < NT; j++) {
        int hwp = yt * WID + xt[j];
#pragma unroll
        for (int ot = 0; ot < 4; ot++) {
            int ob = ot * 16 + q * 4;
            int plane = ob >> 3;
            int intra = ob & 7;
            float4 bb = *(const float4*)&bias[ob];
            half4v r;
            r[0] = (_Float16)(acc[j][ot][0] + bb.x);
            r[1] = (_Float16)(acc[j][ot][1] + bb.y);
            r[2] = (_Float16)(acc[j][ot][2] + bb.z);
            r[3] = (_Float16)(acc[j][ot][3] + bb.w);
            *(half4v*)&outp[(size_t)b * HW * 64 + (size_t)plane * HW * 8
                            + (size_t)hwp * 8 + intra] = r;
        }
    }
}

// ---------------------------------------------------------------------------
// K4: h = x1_final + x2 (plane fp16); out = h @ w_out^T + b_out + x (NCHW fp32)
// ---------------------------------------------------------------------------
__global__ __launch_bounds__(256) void k_merge_out(
    const _Float16* __restrict__ x1f, const _Float16* __restrict__ x2,
    const float* __restrict__ xin, const float* __restrict__ w_out,
    const float* __restrict__ b_out, float* __restrict__ out)
{
    int p  = blockIdx.x * 256 + threadIdx.x;
    int b  = p / HW;
    int hw = p % HW;

    const _Float16* a1 = x1f + (size_t)b * HW * 64 + (size_t)hw * 8;
    const _Float16* a2 = x2  + (size_t)b * HW * 64 + (size_t)hw * 8;
    float v[64];
#pragma unroll
    for (int pl = 0; pl < 8; pl++) {
        half8v u1 = *(const half8v*)&a1[(size_t)pl * HW * 8];
        half8v u2 = *(const half8v*)&a2[(size_t)pl * HW * 8];
#pragma unroll
        for (int j = 0; j < 8; j++)
            v[pl * 8 + j] = (float)u1[j] + (float)u2[j];
    }

    size_t base = (size_t)b * CB * HW + hw;
    for (int o = 0; o < 64; o++) {
        float a = b_out[o] + xin[base + (size_t)o * HW];
#pragma unroll
        for (int c = 0; c < 64; c++) a += v[c] * w_out[o * 64 + c];
        out[base + (size_t)o * HW] = a;
    }
}

// ---------------------------------------------------------------------------
// Launch. Workspace: x1a/x1b/x2 plane fp16 (18.9 MB each), off tap-major
// float2 planes (50 planes * NPOS * 8B = 59 MB), fp16 weights (~1.3 MB).
// ---------------------------------------------------------------------------
extern "C" void kernel_launch(void* const* d_in, const int* in_sizes, int n_in,
                              void* d_out, int out_size, void* d_ws, size_t ws_size,
                              hipStream_t stream)
{
    const float* x     = (const float*)d_in[0];
    const float* ln_w  = (const float*)d_in[1];
    const float* ln_b  = (const float*)d_in[2];
    const float* w_in  = (const float*)d_in[3];
    const float* b_in  = (const float*)d_in[4];
    const float* w_out = (const float*)d_in[5];
    const float* b_out = (const float*)d_in[6];
    const float* dw1   = (const float*)d_in[7];
    const float* db1   = (const float*)d_in[8];
    const float* dw2   = (const float*)d_in[9];
    const float* db2   = (const float*)d_in[10];
    const float* dw3   = (const float*)d_in[11];
    const float* db3   = (const float*)d_in[12];
    const float* ow1   = (const float*)d_in[13];
    const float* ob1   = (const float*)d_in[14];
    const float* ow2   = (const float*)d_in[15];
    const float* ob2   = (const float*)d_in[16];
    const float* ow3   = (const float*)d_in[17];
    const float* ob3   = (const float*)d_in[18];

    _Float16* x1a = (_Float16*)d_ws;
    _Float16* x1b = x1a + (size_t)NPOS * 64;
    _Float16* x2  = x1b + (size_t)NPOS * 64;
    float* off = (float*)(x2 + (size_t)NPOS * 64);
    _Float16* wtd1 = (_Float16*)(off + (size_t)NPOS * 100);
    _Float16* wtd2 = wtd1 + 49 * 64 * 64;
    _Float16* wtd3 = wtd2 + 25 * 64 * 64;
    _Float16* wto1 = wtd3 +  9 * 64 * 64;
    _Float16* wto2 = wto1 + 25 * 112 * 64;
    _Float16* wto3 = wto2 + 25 * 64 * 64;

    // weight prep (fp16, [tap][o][c])
    k_wth<49, 64,  64><<<784, 256, 0, stream>>>(dw1, wtd1);
    k_wth<25, 64,  64><<<400, 256, 0, stream>>>(dw2, wtd2);
    k_wth< 9, 64,  64><<<144, 256, 0, stream>>>(dw3, wtd3);
    k_wth<25, 98, 112><<<700, 256, 0, stream>>>(ow1, wto1);
    k_wth<25, 50,  64><<<400, 256, 0, stream>>>(ow2, wto2);
    k_wth< 9, 18,  32><<< 72, 256, 0, stream>>>(ow3, wto3);

    k_ln_conv_in<<<NPOS / 256, 256, 0, stream>>>(x, ln_w, ln_b, w_in, b_in, x1a, x2);

    // offset convs: proven barrier-free k_mconv (NT=2, 1152 blocks)
    // deform convs: LDS-staged k_sconv v2 (16x16 spatial tiles, 576 blocks, 512 thr)
    // stage 1
    k_mconv<5, 2, 7, 98, 2, false><<<1152, 256, 0, stream>>>(x1a, off, wto1, ob1, off);
    k_sconv<7, 3, 4><<<576, 512, 0, stream>>>(x1a, off, wtd1, db1, x1b);
    // stage 2
    k_mconv<5, 2, 4, 50, 2, false><<<1152, 256, 0, stream>>>(x1b, off, wto2, ob2, off);
    k_sconv<5, 2, 3><<<576, 512, 0, stream>>>(x1b, off, wtd2, db2, x1a);
    // stage 3
    k_mconv<3, 1, 2, 18, 2, false><<<1152, 256, 0, stream>>>(x1a, off, wto3, ob3, off);
    k_sconv<3, 1, 2><<<576, 512, 0, stream>>>(x1a, off, wtd3, db3, x1b);

    k_merge_out<<<NPOS / 256, 256, 0, stream>>>(x1b, x2, x, w_out, b_out, (float*)d_out);
}

// Round 3
// 1185.321 us; speedup vs baseline: 1.5806x; 1.5806x over previous
//
#include <hip/hip_runtime.h>

// Problem constants (B=4, C=64, H=W=192)
#define HH 192
#define WID 192
#define HW (HH*WID)          // 36864
#define CB 64
#define BB 4
#define NPOS (BB*HW)         // 147456

typedef __attribute__((ext_vector_type(8))) _Float16 half8v;
typedef __attribute__((ext_vector_type(4))) _Float16 half4v;
typedef __attribute__((ext_vector_type(8))) unsigned short ushort8;
typedef __attribute__((ext_vector_type(4))) float f32x4;

static __device__ inline half8v splat8(_Float16 x) {
    half8v v = {x, x, x, x, x, x, x, x};
    return v;
}

// x tensors: CHANNEL-PLANE fp16 layout x[b][plane=c>>3][hw][8ch] (16B/pos/plane).
// Offsets: TAP-MAJOR float2 planes off[k][global_pos][2] (NPOS float2 per plane).

// ---------------------------------------------------------------------------
// K1: LayerNorm over C + 1x1 conv C->2C; outputs x1/x2 in plane-fp16 layout.
// ---------------------------------------------------------------------------
__global__ __launch_bounds__(256) void k_ln_conv_in(
    const float* __restrict__ x, const float* __restrict__ g, const float* __restrict__ be,
    const float* __restrict__ w_in, const float* __restrict__ b_in,
    _Float16* __restrict__ x1, _Float16* __restrict__ x2)
{
    int p  = blockIdx.x * 256 + threadIdx.x;     // [0, NPOS)
    int b  = p / HW;
    int hw = p % HW;
    const float* xp = x + (size_t)b * CB * HW + hw;

    float v[64];
    float sum = 0.f, sumsq = 0.f;
#pragma unroll
    for (int c = 0; c < 64; c++) {
        float t = xp[c * HW];
        v[c] = t; sum += t; sumsq += t * t;
    }
    float mu  = sum * (1.f / 64.f);
    float var = sumsq * (1.f / 64.f) - mu * mu;
    float inv = rsqrtf(var + 1e-5f);
#pragma unroll
    for (int c = 0; c < 64; c++) v[c] = (v[c] - mu) * inv * g[c] + be[c];

    _Float16* o1 = x1 + (size_t)b * HW * 64 + (size_t)hw * 8;
    _Float16* o2 = x2 + (size_t)b * HW * 64 + (size_t)hw * 8;
    for (int pl = 0; pl < 8; pl++) {            // pl = channel plane (8 ch)
        half8v r1, r2;
#pragma unroll
        for (int j = 0; j < 8; j++) {
            int o = pl * 8 + j;
            float a1 = b_in[o];
            float a2 = b_in[o + 64];
#pragma unroll
            for (int c = 0; c < 64; c++) {
                a1 += v[c] * w_in[o * 64 + c];
                a2 += v[c] * w_in[(o + 64) * 64 + c];
            }
            r1[j] = (_Float16)a1;
            r2[j] = (_Float16)a2;
        }
        *(half8v*)&o1[(size_t)pl * HW * 8] = r1;
        *(half8v*)&o2[(size_t)pl * HW * 8] = r2;
    }
}

// ---------------------------------------------------------------------------
// Weight prep: w[o][c][ki][kj] fp32 (OIHW) -> wt[k][o][c] fp16, o padded to OP.
// ---------------------------------------------------------------------------
template<int KK, int CO, int OP>
__global__ void k_wth(const float* __restrict__ w, _Float16* __restrict__ wt)
{
    int idx = blockIdx.x * 256 + threadIdx.x;
    constexpr int TOT = KK * OP * 64;
    if (idx >= TOT) return;
    int k = idx / (OP * 64);
    int r = idx % (OP * 64);
    int o = r / 64;
    int c = r % 64;
    float v = (o < CO) ? w[((size_t)o * 64 + c) * KK + k] : 0.f;
    wt[idx] = (_Float16)v;
}

// ---------------------------------------------------------------------------
// Corner-register set for one in-flight deform tile-tap.
// ---------------------------------------------------------------------------
struct CornerRegs {
    half8v r[8];             // {00lo,00hi,01lo,01hi,10lo,10hi,11lo,11hi}
    float w00, w01, w10, w11;
};

static __device__ inline void d_issue(const _Float16* __restrict__ xq0,
                                      const _Float16* __restrict__ xq1,
                                      int y, int xg, int ki, int kj, int PAD,
                                      float2 off, CornerRegs& C)
{
    float py = (float)(y + ki - PAD) + off.x;
    float px = (float)(xg + kj - PAD) + off.y;
    float fy = floorf(py), fx = floorf(px);
    float wy = py - fy, wx = px - fx;
    int iy0 = (int)fy, ix0 = (int)fx;
    int iy1 = iy0 + 1, ix1 = ix0 + 1;
    float m00 = (iy0 >= 0 && iy0 < HH && ix0 >= 0 && ix0 < WID) ? 1.f : 0.f;
    float m01 = (iy0 >= 0 && iy0 < HH && ix1 >= 0 && ix1 < WID) ? 1.f : 0.f;
    float m10 = (iy1 >= 0 && iy1 < HH && ix0 >= 0 && ix0 < WID) ? 1.f : 0.f;
    float m11 = (iy1 >= 0 && iy1 < HH && ix1 >= 0 && ix1 < WID) ? 1.f : 0.f;
    int cy0 = min(max(iy0, 0), HH - 1), cy1 = min(max(iy1, 0), HH - 1);
    int cx0 = min(max(ix0, 0), WID - 1), cx1 = min(max(ix1, 0), WID - 1);
    size_t i00 = (size_t)(cy0 * WID + cx0) * 8, i01 = (size_t)(cy0 * WID + cx1) * 8;
    size_t i10 = (size_t)(cy1 * WID + cx0) * 8, i11 = (size_t)(cy1 * WID + cx1) * 8;
    C.r[0] = *(const half8v*)(xq0 + i00);  C.r[1] = *(const half8v*)(xq1 + i00);
    C.r[2] = *(const half8v*)(xq0 + i01);  C.r[3] = *(const half8v*)(xq1 + i01);
    C.r[4] = *(const half8v*)(xq0 + i10);  C.r[5] = *(const half8v*)(xq1 + i10);
    C.r[6] = *(const half8v*)(xq0 + i11);  C.r[7] = *(const half8v*)(xq1 + i11);
    C.w00 = (1.f - wy) * (1.f - wx) * m00;
    C.w01 = (1.f - wy) * wx * m01;
    C.w10 = wy * (1.f - wx) * m10;
    C.w11 = wy * wx * m11;
}

// packed fp16 bilinear combine: ~8 v_pk_fma_f16 per half8v
static __device__ inline void d_combine(const CornerRegs& C, half8v& f0, half8v& f1)
{
    half8v w00v = splat8((_Float16)C.w00);
    half8v w01v = splat8((_Float16)C.w01);
    half8v w10v = splat8((_Float16)C.w10);
    half8v w11v = splat8((_Float16)C.w11);
    f0 = C.r[0] * w00v + C.r[2] * w01v + C.r[4] * w10v + C.r[6] * w11v;
    f1 = C.r[1] * w00v + C.r[3] * w01v + C.r[5] * w10v + C.r[7] * w11v;
}

static __device__ inline void d_issue_conv(const _Float16* __restrict__ xq0,
                                           const _Float16* __restrict__ xq1,
                                           int y, int xg, int ki, int kj, int PAD,
                                           half8v& f0, half8v& f1)
{
    int gy = y + ki - PAD;
    int gx = xg + kj - PAD;
    bool ok = (gy >= 0 && gy < HH && gx >= 0 && gx < WID);
    if (ok) {
        size_t i = (size_t)(gy * WID + gx) * 8;
        f0 = *(const half8v*)(xq0 + i);
        f1 = *(const half8v*)(xq1 + i);
    } else {
        f0 = splat8((_Float16)0.f); f1 = splat8((_Float16)0.f);
    }
}

// ---------------------------------------------------------------------------
// Barrier-free wave-local MFMA conv, plane fp16 layout, NT pos-tiles per wave.
// (kept for the DEFORM=false offset convs; deform path uses k_sconv)
// ---------------------------------------------------------------------------
template<int K, int PAD, int NOT, int CO, int NT, bool DEFORM>
__global__ __launch_bounds__(256) void k_mconv(
    const _Float16* __restrict__ xin, const float* __restrict__ offp,
    const _Float16* __restrict__ wtb, const float* __restrict__ bias,
    void* __restrict__ outv)
{
    constexpr int KK = K * K;
    constexpr int OP = NOT * 16;
    constexpr int KTAP = CO / 2;                 // tap count of the offset consumer
    constexpr int BP = 64 * NT;                  // positions per block

    int p0  = blockIdx.x * BP;
    int b   = p0 / HW;
    int hwb = p0 % HW;

    int t    = threadIdx.x;
    int lane = t & 63;
    int wave = t >> 6;
    int p    = lane & 15;
    int q    = lane >> 4;
    int wlane = p * 8 + q;            // A-frag offset (half8 units)

    // per-tile coordinates
    int yt[NT], xt[NT], gp[NT];
#pragma unroll
    for (int j = 0; j < NT; j++) {
        int hwt = hwb + (wave * NT + j) * 16;
        yt[j] = hwt / WID;
        xt[j] = hwt % WID + p;
        gp[j] = p0 + (wave * NT + j) * 16 + p;
    }

    f32x4 acc[NT][NOT];
#pragma unroll
    for (int j = 0; j < NT; j++)
#pragma unroll
        for (int ot = 0; ot < NOT; ot++) acc[j][ot] = (f32x4){0.f, 0.f, 0.f, 0.f};

    const _Float16* xb  = xin + (size_t)b * HW * 64;
    const _Float16* xq0 = xb + (size_t)q * HW * 8;          // chunk-0 plane
    const _Float16* xq1 = xb + (size_t)(q + 4) * HW * 8;    // chunk-1 plane
    const half8v* wbase = (const half8v*)wtb;

    const float2* offj[NT];
    float2 offc[NT], offn[NT];
    if (DEFORM) {
#pragma unroll
        for (int j = 0; j < NT; j++) {
            offj[j] = (const float2*)offp + gp[j];
            offc[j] = offj[j][0];
        }
    }

    int ki = 0, kj = 0;
    for (int k = 0; k < KK; k++) {
        if (DEFORM) {
#pragma unroll
            for (int j = 0; j < NT; j++)
                offn[j] = offj[j][(size_t)(k + 1) * NPOS];
        }
        const half8v* wp = wbase + (size_t)k * OP * 8;
        half8v aw0[NOT], aw1[NOT];
#pragma unroll
        for (int ot = 0; ot < NOT; ot++) {
            aw0[ot] = wp[ot * 128 + wlane];
            aw1[ot] = wp[ot * 128 + wlane + 4];
        }

        if (DEFORM) {
            CornerRegs CC[2];
            d_issue(xq0, xq1, yt[0], xt[0], ki, kj, PAD, offc[0], CC[0]);
#pragma unroll
            for (int j = 0; j < NT; j++) {
                if (j + 1 < NT)
                    d_issue(xq0, xq1, yt[j + 1], xt[j + 1], ki, kj, PAD, offc[j + 1], CC[(j + 1) & 1]);
                half8v f0, f1;
                d_combine(CC[j & 1], f0, f1);
#pragma unroll
                for (int ot = 0; ot < NOT; ot++)
                    acc[j][ot] = __builtin_amdgcn_mfma_f32_16x16x32_f16(aw0[ot], f0, acc[j][ot], 0, 0, 0);
#pragma unroll
                for (int ot = 0; ot < NOT; ot++)
                    acc[j][ot] = __builtin_amdgcn_mfma_f32_16x16x32_f16(aw1[ot], f1, acc[j][ot], 0, 0, 0);
            }
#pragma unroll
            for (int j = 0; j < NT; j++) offc[j] = offn[j];
        } else {
            half8v f0[NT], f1[NT];
#pragma unroll
            for (int j = 0; j < NT; j++)
                d_issue_conv(xq0, xq1, yt[j], xt[j], ki, kj, PAD, f0[j], f1[j]);
#pragma unroll
            for (int j = 0; j < NT; j++) {
#pragma unroll
                for (int ot = 0; ot < NOT; ot++)
                    acc[j][ot] = __builtin_amdgcn_mfma_f32_16x16x32_f16(aw0[ot], f0[j], acc[j][ot], 0, 0, 0);
#pragma unroll
                for (int ot = 0; ot < NOT; ot++)
                    acc[j][ot] = __builtin_amdgcn_mfma_f32_16x16x32_f16(aw1[ot], f1[j], acc[j][ot], 0, 0, 0);
            }
        }

        kj++;
        if (kj == K) { kj = 0; ki++; }
    }

    // ---- epilogue: D reg i -> o = ot*16 + q*4 + i, pos = gp[j] ----
    if (DEFORM) {
        _Float16* outp = (_Float16*)outv;
#pragma unroll
        for (int j = 0; j < NT; j++) {
            int hwp = hwb + (wave * NT + j) * 16 + p;
#pragma unroll
            for (int ot = 0; ot < NOT; ot++) {
                int ob = ot * 16 + q * 4;
                int plane = ob >> 3;
                int intra = ob & 7;
                float4 bb = *(const float4*)&bias[ob];
                half4v r;
                r[0] = (_Float16)(acc[j][ot][0] + bb.x);
                r[1] = (_Float16)(acc[j][ot][1] + bb.y);
                r[2] = (_Float16)(acc[j][ot][2] + bb.z);
                r[3] = (_Float16)(acc[j][ot][3] + bb.w);
                *(half4v*)&outp[(size_t)b * HW * 64 + (size_t)plane * HW * 8
                                + (size_t)hwp * 8 + intra] = r;
            }
        }
    } else {
        float* outf = (float*)outv;   // tap-major float2 planes
#pragma unroll
        for (int j = 0; j < NT; j++) {
#pragma unroll
            for (int ot = 0; ot < NOT; ot++) {
                int ob = ot * 16 + q * 4;     // channels ob..ob+3 = taps ob/2, ob/2+1
                int t0 = ob >> 1;
                if (t0 < KTAP) {
                    float2 r; r.x = acc[j][ot][0] + bias[ob];     r.y = acc[j][ot][1] + bias[ob + 1];
                    *(float2*)&outf[((size_t)t0 * NPOS + gp[j]) * 2] = r;
                }
                if (t0 + 1 < KTAP) {
                    float2 r; r.x = acc[j][ot][2] + bias[ob + 2]; r.y = acc[j][ot][3] + bias[ob + 3];
                    *(float2*)&outf[((size_t)(t0 + 1) * NPOS + gp[j]) * 2] = r;
                }
            }
        }
    }
}

// ---------------------------------------------------------------------------
// k_sconv v3: LDS-staged deform conv. Block = 16x16 positions, 512 threads
// (8 waves x NT=2 tiles of 2rows x 8cols). Staged region (16+2H)^2 pixels,
// 128 B/pixel: 72 KB (K=7) / 60.5 KB (K=5) / 50 KB (K=3) -> 2-3 blocks/CU.
// LESSON (round 2): __launch_bounds__(512, 4) capped VGPRs at 64 -> massive
// scratch spill (WRITE_SIZE 18MB -> 1.4GB, 738us). Plain (512) lets the
// compiler take the ~84-100 VGPR it needs; LDS is the occupancy limiter.
// Swizzle: v1's proven col-only 16B-slot swizzle slot = pl ^ (col & 7)
// (13.9M conflict cycles measured; round-2's row-aware variant regressed).
// Per-lane global fallback when a corner exits the halo (|off|>=1).
// Numerics identical to v1/v2 (same fp16 samples/combine/MFMA order).
// ---------------------------------------------------------------------------
template<int K, int PAD, int HALO>
__global__ __launch_bounds__(512) void k_sconv(
    const _Float16* __restrict__ xin, const float* __restrict__ offp,
    const _Float16* __restrict__ wtb, const float* __restrict__ bias,
    _Float16* __restrict__ outp)
{
    constexpr int KK = K * K;
    constexpr int RB = 16 + 2 * HALO;     // staged rows
    constexpr int WB = 16 + 2 * HALO;     // staged cols
    constexpr int NT = 2;

    __shared__ half8v sm[RB * WB * 8];    // 16B slot per (pixel, plane)

    int bi  = blockIdx.x;
    int b   = bi / 144;                   // 144 = 12 row-tiles * 12 col-tiles
    int tt  = bi % 144;
    int by0 = (tt / 12) * 16;
    int bx0 = (tt % 12) * 16;
    int ry0 = by0 - HALO;
    int rx0 = bx0 - HALO;

    const _Float16* xb  = xin + (size_t)b * HW * 64;

    // ---- stage tile + halo (edge-clamped rows/cols) ----
    constexpr int CH = RB * WB * 8;       // 16B chunks
    for (int i = threadIdx.x; i < CH; i += 512) {
        int cc = i % WB;
        int rp = i / WB;
        int pl = rp & 7;
        int r  = rp >> 3;
        int yr = min(max(ry0 + r,  0), HH - 1);
        int xc = min(max(rx0 + cc, 0), WID - 1);
        half8v ch = *(const half8v*)(xb + ((size_t)pl * HW + (size_t)(yr * WID + xc)) * 8);
        sm[(r * WB + cc) * 8 + (pl ^ (cc & 7))] = ch;
    }
    __syncthreads();

    int t    = threadIdx.x;
    int lane = t & 63;
    int wave = t >> 6;                    // 0..7
    int p    = lane & 15;
    int q    = lane >> 4;
    int wlane = p * 8 + q;
    int dr   = p >> 3;                    // tile-local row (0..1)
    int dc   = p & 7;                     // tile-local col (0..7)

    const _Float16* xq0 = xb + (size_t)q * HW * 8;        // fallback planes
    const _Float16* xq1 = xb + (size_t)(q + 4) * HW * 8;
    const half8v* wbase = (const half8v*)wtb;

    int yt = by0 + wave * 2 + dr;         // same row pair for both tiles
    int xt[NT], gp[NT];
#pragma unroll
    for (int j = 0; j < NT; j++) {
        xt[j] = bx0 + j * 8 + dc;
        gp[j] = b * HW + yt * WID + xt[j];
    }

    f32x4 acc[NT][4];
#pragma unroll
    for (int j = 0; j < NT; j++)
#pragma unroll
        for (int ot = 0; ot < 4; ot++) acc[j][ot] = (f32x4){0.f, 0.f, 0.f, 0.f};

    const float2* offj[NT];
    float2 offc[NT], offn[NT];
#pragma unroll
    for (int j = 0; j < NT; j++) {
        offj[j] = (const float2*)offp + gp[j];
        offc[j] = offj[j][0];
    }

    // corner fetch for one tile-tap (fast: swizzled LDS; rare fallback: global)
    auto fetch = [&](int xg, int ki, int kj, float2 off, CornerRegs& C) {
        float py = (float)(yt + ki - PAD) + off.x;
        float px = (float)(xg + kj - PAD) + off.y;
        float fy = floorf(py), fx = floorf(px);
        float wy = py - fy, wx = px - fx;
        int iy0 = (int)fy, ix0 = (int)fx;
        int iy1 = iy0 + 1, ix1 = ix0 + 1;
        float m00 = (iy0 >= 0 && iy0 < HH && ix0 >= 0 && ix0 < WID) ? 1.f : 0.f;
        float m01 = (iy0 >= 0 && iy0 < HH && ix1 >= 0 && ix1 < WID) ? 1.f : 0.f;
        float m10 = (iy1 >= 0 && iy1 < HH && ix0 >= 0 && ix0 < WID) ? 1.f : 0.f;
        float m11 = (iy1 >= 0 && iy1 < HH && ix1 >= 0 && ix1 < WID) ? 1.f : 0.f;
        C.w00 = (1.f - wy) * (1.f - wx) * m00;
        C.w01 = (1.f - wy) * wx * m01;
        C.w10 = wy * (1.f - wx) * m10;
        C.w11 = wy * wx * m11;
        bool fast = (iy0 >= ry0) && (iy1 <= ry0 + RB - 1) &&
                    (ix0 >= rx0) && (ix1 <= rx0 + WB - 1);
        if (__builtin_expect(fast, 1)) {
            int r0 = iy0 - ry0, c0 = ix0 - rx0;
            int p00 = r0 * WB + c0;
            int m0 = c0 & 7;                     // slot key: col-only (v1)
            int m1 = (c0 + 1) & 7;
            C.r[0] = sm[p00 * 8            + ( q      ^ m0)];
            C.r[1] = sm[p00 * 8            + ((q + 4) ^ m0)];
            C.r[2] = sm[(p00 + 1) * 8      + ( q      ^ m1)];
            C.r[3] = sm[(p00 + 1) * 8      + ((q + 4) ^ m1)];
            C.r[4] = sm[(p00 + WB) * 8     + ( q      ^ m0)];
            C.r[5] = sm[(p00 + WB) * 8     + ((q + 4) ^ m0)];
            C.r[6] = sm[(p00 + WB + 1) * 8 + ( q      ^ m1)];
            C.r[7] = sm[(p00 + WB + 1) * 8 + ((q + 4) ^ m1)];
        } else {
            int cy0 = min(max(iy0, 0), HH - 1), cy1 = min(max(iy1, 0), HH - 1);
            int cx0 = min(max(ix0, 0), WID - 1), cx1 = min(max(ix1, 0), WID - 1);
            size_t i00 = (size_t)(cy0 * WID + cx0) * 8, i01 = (size_t)(cy0 * WID + cx1) * 8;
            size_t i10 = (size_t)(cy1 * WID + cx0) * 8, i11 = (size_t)(cy1 * WID + cx1) * 8;
            C.r[0] = *(const half8v*)(xq0 + i00);  C.r[1] = *(const half8v*)(xq1 + i00);
            C.r[2] = *(const half8v*)(xq0 + i01);  C.r[3] = *(const half8v*)(xq1 + i01);
            C.r[4] = *(const half8v*)(xq0 + i10);  C.r[5] = *(const half8v*)(xq1 + i10);
            C.r[6] = *(const half8v*)(xq0 + i11);  C.r[7] = *(const half8v*)(xq1 + i11);
        }
    };

    int ki = 0, kj = 0;
    for (int k = 0; k < KK; k++) {
#pragma unroll
        for (int j = 0; j < NT; j++)
            offn[j] = offj[j][(size_t)(k + 1) * NPOS];

        const half8v* wp = wbase + (size_t)k * 64 * 8;   // OP = 64
        half8v aw0[4], aw1[4];
#pragma unroll
        for (int ot = 0; ot < 4; ot++) {
            aw0[ot] = wp[ot * 128 + wlane];
            aw1[ot] = wp[ot * 128 + wlane + 4];
        }

        CornerRegs CC[2];
        fetch(xt[0], ki, kj, offc[0], CC[0]);
#pragma unroll
        for (int j = 0; j < NT; j++) {
            if (j + 1 < NT)
                fetch(xt[j + 1], ki, kj, offc[j + 1], CC[(j + 1) & 1]);
            half8v f0, f1;
            d_combine(CC[j & 1], f0, f1);
#pragma unroll
            for (int ot = 0; ot < 4; ot++)
                acc[j][ot] = __builtin_amdgcn_mfma_f32_16x16x32_f16(aw0[ot], f0, acc[j][ot], 0, 0, 0);
#pragma unroll
            for (int ot = 0; ot < 4; ot++)
                acc[j][ot] = __builtin_amdgcn_mfma_f32_16x16x32_f16(aw1[ot], f1, acc[j][ot], 0, 0, 0);
        }
#pragma unroll
        for (int j = 0; j < NT; j++) offc[j] = offn[j];

        kj++;
        if (kj == K) { kj = 0; ki++; }
    }

    // ---- epilogue: D reg i -> o = ot*16 + q*4 + i, pos = (yt, xt[j]) ----
#pragma unroll
    for (int j = 0; j < NT; j++) {
        int hwp = yt * WID + xt[j];
#pragma unroll
        for (int ot = 0; ot < 4; ot++) {
            int ob = ot * 16 + q * 4;
            int plane = ob >> 3;
            int intra = ob & 7;
            float4 bb = *(const float4*)&bias[ob];
            half4v r;
            r[0] = (_Float16)(acc[j][ot][0] + bb.x);
            r[1] = (_Float16)(acc[j][ot][1] + bb.y);
            r[2] = (_Float16)(acc[j][ot][2] + bb.z);
            r[3] = (_Float16)(acc[j][ot][3] + bb.w);
            *(half4v*)&outp[(size_t)b * HW * 64 + (size_t)plane * HW * 8
                            + (size_t)hwp * 8 + intra] = r;
        }
    }
}

// ---------------------------------------------------------------------------
// K4: h = x1_final + x2 (plane fp16); out = h @ w_out^T + b_out + x (NCHW fp32)
// ---------------------------------------------------------------------------
__global__ __launch_bounds__(256) void k_merge_out(
    const _Float16* __restrict__ x1f, const _Float16* __restrict__ x2,
    const float* __restrict__ xin, const float* __restrict__ w_out,
    const float* __restrict__ b_out, float* __restrict__ out)
{
    int p  = blockIdx.x * 256 + threadIdx.x;
    int b  = p / HW;
    int hw = p % HW;

    const _Float16* a1 = x1f + (size_t)b * HW * 64 + (size_t)hw * 8;
    const _Float16* a2 = x2  + (size_t)b * HW * 64 + (size_t)hw * 8;
    float v[64];
#pragma unroll
    for (int pl = 0; pl < 8; pl++) {
        half8v u1 = *(const half8v*)&a1[(size_t)pl * HW * 8];
        half8v u2 = *(const half8v*)&a2[(size_t)pl * HW * 8];
#pragma unroll
        for (int j = 0; j < 8; j++)
            v[pl * 8 + j] = (float)u1[j] + (float)u2[j];
    }

    size_t base = (size_t)b * CB * HW + hw;
    for (int o = 0; o < 64; o++) {
        float a = b_out[o] + xin[base + (size_t)o * HW];
#pragma unroll
        for (int c = 0; c < 64; c++) a += v[c] * w_out[o * 64 + c];
        out[base + (size_t)o * HW] = a;
    }
}

// ---------------------------------------------------------------------------
// Launch. Workspace: x1a/x1b/x2 plane fp16 (18.9 MB each), off tap-major
// float2 planes (50 planes * NPOS * 8B = 59 MB), fp16 weights (~1.3 MB).
// ---------------------------------------------------------------------------
extern "C" void kernel_launch(void* const* d_in, const int* in_sizes, int n_in,
                              void* d_out, int out_size, void* d_ws, size_t ws_size,
                              hipStream_t stream)
{
    const float* x     = (const float*)d_in[0];
    const float* ln_w  = (const float*)d_in[1];
    const float* ln_b  = (const float*)d_in[2];
    const float* w_in  = (const float*)d_in[3];
    const float* b_in  = (const float*)d_in[4];
    const float* w_out = (const float*)d_in[5];
    const float* b_out = (const float*)d_in[6];
    const float* dw1   = (const float*)d_in[7];
    const float* db1   = (const float*)d_in[8];
    const float* dw2   = (const float*)d_in[9];
    const float* db2   = (const float*)d_in[10];
    const float* dw3   = (const float*)d_in[11];
    const float* db3   = (const float*)d_in[12];
    const float* ow1   = (const float*)d_in[13];
    const float* ob1   = (const float*)d_in[14];
    const float* ow2   = (const float*)d_in[15];
    const float* ob2   = (const float*)d_in[16];
    const float* ow3   = (const float*)d_in[17];
    const float* ob3   = (const float*)d_in[18];

    _Float16* x1a = (_Float16*)d_ws;
    _Float16* x1b = x1a + (size_t)NPOS * 64;
    _Float16* x2  = x1b + (size_t)NPOS * 64;
    float* off = (float*)(x2 + (size_t)NPOS * 64);
    _Float16* wtd1 = (_Float16*)(off + (size_t)NPOS * 100);
    _Float16* wtd2 = wtd1 + 49 * 64 * 64;
    _Float16* wtd3 = wtd2 + 25 * 64 * 64;
    _Float16* wto1 = wtd3 +  9 * 64 * 64;
    _Float16* wto2 = wto1 + 25 * 112 * 64;
    _Float16* wto3 = wto2 + 25 * 64 * 64;

    // weight prep (fp16, [tap][o][c])
    k_wth<49, 64,  64><<<784, 256, 0, stream>>>(dw1, wtd1);
    k_wth<25, 64,  64><<<400, 256, 0, stream>>>(dw2, wtd2);
    k_wth< 9, 64,  64><<<144, 256, 0, stream>>>(dw3, wtd3);
    k_wth<25, 98, 112><<<700, 256, 0, stream>>>(ow1, wto1);
    k_wth<25, 50,  64><<<400, 256, 0, stream>>>(ow2, wto2);
    k_wth< 9, 18,  32><<< 72, 256, 0, stream>>>(ow3, wto3);

    k_ln_conv_in<<<NPOS / 256, 256, 0, stream>>>(x, ln_w, ln_b, w_in, b_in, x1a, x2);

    // offset convs: proven barrier-free k_mconv (NT=2, 1152 blocks)
    // deform convs: LDS-staged k_sconv v3 (16x16 spatial tiles, 576 blocks, 512 thr)
    // stage 1
    k_mconv<5, 2, 7, 98, 2, false><<<1152, 256, 0, stream>>>(x1a, off, wto1, ob1, off);
    k_sconv<7, 3, 4><<<576, 512, 0, stream>>>(x1a, off, wtd1, db1, x1b);
    // stage 2
    k_mconv<5, 2, 4, 50, 2, false><<<1152, 256, 0, stream>>>(x1b, off, wto2, ob2, off);
    k_sconv<5, 2, 3><<<576, 512, 0, stream>>>(x1b, off, wtd2, db2, x1a);
    // stage 3
    k_mconv<3, 1, 2, 18, 2, false><<<1152, 256, 0, stream>>>(x1a, off, wto3, ob3, off);
    k_sconv<3, 1, 2><<<576, 512, 0, stream>>>(x1a, off, wtd3, db3, x1b);

    k_merge_out<<<NPOS / 256, 256, 0, stream>>>(x1b, x2, x, w_out, b_out, (float*)d_out);
}

// Round 4
// 1179.361 us; speedup vs baseline: 1.5886x; 1.0051x over previous
//
#include <hip/hip_runtime.h>

// Problem constants (B=4, C=64, H=W=192)
#define HH 192
#define WID 192
#define HW (HH*WID)          // 36864
#define CB 64
#define BB 4
#define NPOS (BB*HW)         // 147456

typedef __attribute__((ext_vector_type(8))) _Float16 half8v;
typedef __attribute__((ext_vector_type(4))) _Float16 half4v;
typedef __attribute__((ext_vector_type(8))) unsigned short ushort8;
typedef __attribute__((ext_vector_type(4))) float f32x4;

static __device__ inline half8v splat8(_Float16 x) {
    half8v v = {x, x, x, x, x, x, x, x};
    return v;
}

// x tensors: CHANNEL-PLANE fp16 layout x[b][plane=c>>3][hw][8ch] (16B/pos/plane).
// Offsets: TAP-MAJOR float2 planes off[k][global_pos][2] (NPOS float2 per plane).

// ---------------------------------------------------------------------------
// K1: LayerNorm over C + 1x1 conv C->2C; outputs x1/x2 in plane-fp16 layout.
// ---------------------------------------------------------------------------
__global__ __launch_bounds__(256) void k_ln_conv_in(
    const float* __restrict__ x, const float* __restrict__ g, const float* __restrict__ be,
    const float* __restrict__ w_in, const float* __restrict__ b_in,
    _Float16* __restrict__ x1, _Float16* __restrict__ x2)
{
    int p  = blockIdx.x * 256 + threadIdx.x;     // [0, NPOS)
    int b  = p / HW;
    int hw = p % HW;
    const float* xp = x + (size_t)b * CB * HW + hw;

    float v[64];
    float sum = 0.f, sumsq = 0.f;
#pragma unroll
    for (int c = 0; c < 64; c++) {
        float t = xp[c * HW];
        v[c] = t; sum += t; sumsq += t * t;
    }
    float mu  = sum * (1.f / 64.f);
    float var = sumsq * (1.f / 64.f) - mu * mu;
    float inv = rsqrtf(var + 1e-5f);
#pragma unroll
    for (int c = 0; c < 64; c++) v[c] = (v[c] - mu) * inv * g[c] + be[c];

    _Float16* o1 = x1 + (size_t)b * HW * 64 + (size_t)hw * 8;
    _Float16* o2 = x2 + (size_t)b * HW * 64 + (size_t)hw * 8;
    for (int pl = 0; pl < 8; pl++) {            // pl = channel plane (8 ch)
        half8v r1, r2;
#pragma unroll
        for (int j = 0; j < 8; j++) {
            int o = pl * 8 + j;
            float a1 = b_in[o];
            float a2 = b_in[o + 64];
#pragma unroll
            for (int c = 0; c < 64; c++) {
                a1 += v[c] * w_in[o * 64 + c];
                a2 += v[c] * w_in[(o + 64) * 64 + c];
            }
            r1[j] = (_Float16)a1;
            r2[j] = (_Float16)a2;
        }
        *(half8v*)&o1[(size_t)pl * HW * 8] = r1;
        *(half8v*)&o2[(size_t)pl * HW * 8] = r2;
    }
}

// ---------------------------------------------------------------------------
// Weight prep: w[o][c][ki][kj] fp32 (OIHW) -> wt[k][o][c] fp16, o padded to OP.
// ---------------------------------------------------------------------------
template<int KK, int CO, int OP>
__global__ void k_wth(const float* __restrict__ w, _Float16* __restrict__ wt)
{
    int idx = blockIdx.x * 256 + threadIdx.x;
    constexpr int TOT = KK * OP * 64;
    if (idx >= TOT) return;
    int k = idx / (OP * 64);
    int r = idx % (OP * 64);
    int o = r / 64;
    int c = r % 64;
    float v = (o < CO) ? w[((size_t)o * 64 + c) * KK + k] : 0.f;
    wt[idx] = (_Float16)v;
}

// ---------------------------------------------------------------------------
// Corner-register set for one in-flight deform tile-tap.
// ---------------------------------------------------------------------------
struct CornerRegs {
    half8v r[8];             // {00lo,00hi,01lo,01hi,10lo,10hi,11lo,11hi}
    float w00, w01, w10, w11;
};

static __device__ inline void d_issue(const _Float16* __restrict__ xq0,
                                      const _Float16* __restrict__ xq1,
                                      int y, int xg, int ki, int kj, int PAD,
                                      float2 off, CornerRegs& C)
{
    float py = (float)(y + ki - PAD) + off.x;
    float px = (float)(xg + kj - PAD) + off.y;
    float fy = floorf(py), fx = floorf(px);
    float wy = py - fy, wx = px - fx;
    int iy0 = (int)fy, ix0 = (int)fx;
    int iy1 = iy0 + 1, ix1 = ix0 + 1;
    float m00 = (iy0 >= 0 && iy0 < HH && ix0 >= 0 && ix0 < WID) ? 1.f : 0.f;
    float m01 = (iy0 >= 0 && iy0 < HH && ix1 >= 0 && ix1 < WID) ? 1.f : 0.f;
    float m10 = (iy1 >= 0 && iy1 < HH && ix0 >= 0 && ix0 < WID) ? 1.f : 0.f;
    float m11 = (iy1 >= 0 && iy1 < HH && ix1 >= 0 && ix1 < WID) ? 1.f : 0.f;
    int cy0 = min(max(iy0, 0), HH - 1), cy1 = min(max(iy1, 0), HH - 1);
    int cx0 = min(max(ix0, 0), WID - 1), cx1 = min(max(ix1, 0), WID - 1);
    size_t i00 = (size_t)(cy0 * WID + cx0) * 8, i01 = (size_t)(cy0 * WID + cx1) * 8;
    size_t i10 = (size_t)(cy1 * WID + cx0) * 8, i11 = (size_t)(cy1 * WID + cx1) * 8;
    C.r[0] = *(const half8v*)(xq0 + i00);  C.r[1] = *(const half8v*)(xq1 + i00);
    C.r[2] = *(const half8v*)(xq0 + i01);  C.r[3] = *(const half8v*)(xq1 + i01);
    C.r[4] = *(const half8v*)(xq0 + i10);  C.r[5] = *(const half8v*)(xq1 + i10);
    C.r[6] = *(const half8v*)(xq0 + i11);  C.r[7] = *(const half8v*)(xq1 + i11);
    C.w00 = (1.f - wy) * (1.f - wx) * m00;
    C.w01 = (1.f - wy) * wx * m01;
    C.w10 = wy * (1.f - wx) * m10;
    C.w11 = wy * wx * m11;
}

// packed fp16 bilinear combine: ~8 v_pk_fma_f16 per half8v
static __device__ inline void d_combine(const CornerRegs& C, half8v& f0, half8v& f1)
{
    half8v w00v = splat8((_Float16)C.w00);
    half8v w01v = splat8((_Float16)C.w01);
    half8v w10v = splat8((_Float16)C.w10);
    half8v w11v = splat8((_Float16)C.w11);
    f0 = C.r[0] * w00v + C.r[2] * w01v + C.r[4] * w10v + C.r[6] * w11v;
    f1 = C.r[1] * w00v + C.r[3] * w01v + C.r[5] * w10v + C.r[7] * w11v;
}

static __device__ inline void d_issue_conv(const _Float16* __restrict__ xq0,
                                           const _Float16* __restrict__ xq1,
                                           int y, int xg, int ki, int kj, int PAD,
                                           half8v& f0, half8v& f1)
{
    int gy = y + ki - PAD;
    int gx = xg + kj - PAD;
    bool ok = (gy >= 0 && gy < HH && gx >= 0 && gx < WID);
    if (ok) {
        size_t i = (size_t)(gy * WID + gx) * 8;
        f0 = *(const half8v*)(xq0 + i);
        f1 = *(const half8v*)(xq1 + i);
    } else {
        f0 = splat8((_Float16)0.f); f1 = splat8((_Float16)0.f);
    }
}

// ---------------------------------------------------------------------------
// Barrier-free wave-local MFMA conv, plane fp16 layout, NT pos-tiles per wave.
// (kept for the DEFORM=false offset convs; deform path uses k_sconv)
// ---------------------------------------------------------------------------
template<int K, int PAD, int NOT, int CO, int NT, bool DEFORM>
__global__ __launch_bounds__(256) void k_mconv(
    const _Float16* __restrict__ xin, const float* __restrict__ offp,
    const _Float16* __restrict__ wtb, const float* __restrict__ bias,
    void* __restrict__ outv)
{
    constexpr int KK = K * K;
    constexpr int OP = NOT * 16;
    constexpr int KTAP = CO / 2;                 // tap count of the offset consumer
    constexpr int BP = 64 * NT;                  // positions per block

    int p0  = blockIdx.x * BP;
    int b   = p0 / HW;
    int hwb = p0 % HW;

    int t    = threadIdx.x;
    int lane = t & 63;
    int wave = t >> 6;
    int p    = lane & 15;
    int q    = lane >> 4;
    int wlane = p * 8 + q;            // A-frag offset (half8 units)

    // per-tile coordinates
    int yt[NT], xt[NT], gp[NT];
#pragma unroll
    for (int j = 0; j < NT; j++) {
        int hwt = hwb + (wave * NT + j) * 16;
        yt[j] = hwt / WID;
        xt[j] = hwt % WID + p;
        gp[j] = p0 + (wave * NT + j) * 16 + p;
    }

    f32x4 acc[NT][NOT];
#pragma unroll
    for (int j = 0; j < NT; j++)
#pragma unroll
        for (int ot = 0; ot < NOT; ot++) acc[j][ot] = (f32x4){0.f, 0.f, 0.f, 0.f};

    const _Float16* xb  = xin + (size_t)b * HW * 64;
    const _Float16* xq0 = xb + (size_t)q * HW * 8;          // chunk-0 plane
    const _Float16* xq1 = xb + (size_t)(q + 4) * HW * 8;    // chunk-1 plane
    const half8v* wbase = (const half8v*)wtb;

    const float2* offj[NT];
    float2 offc[NT], offn[NT];
    if (DEFORM) {
#pragma unroll
        for (int j = 0; j < NT; j++) {
            offj[j] = (const float2*)offp + gp[j];
            offc[j] = offj[j][0];
        }
    }

    int ki = 0, kj = 0;
    for (int k = 0; k < KK; k++) {
        if (DEFORM) {
#pragma unroll
            for (int j = 0; j < NT; j++)
                offn[j] = offj[j][(size_t)(k + 1) * NPOS];
        }
        const half8v* wp = wbase + (size_t)k * OP * 8;
        half8v aw0[NOT], aw1[NOT];
#pragma unroll
        for (int ot = 0; ot < NOT; ot++) {
            aw0[ot] = wp[ot * 128 + wlane];
            aw1[ot] = wp[ot * 128 + wlane + 4];
        }

        if (DEFORM) {
            CornerRegs CC[2];
            d_issue(xq0, xq1, yt[0], xt[0], ki, kj, PAD, offc[0], CC[0]);
#pragma unroll
            for (int j = 0; j < NT; j++) {
                if (j + 1 < NT)
                    d_issue(xq0, xq1, yt[j + 1], xt[j + 1], ki, kj, PAD, offc[j + 1], CC[(j + 1) & 1]);
                half8v f0, f1;
                d_combine(CC[j & 1], f0, f1);
#pragma unroll
                for (int ot = 0; ot < NOT; ot++)
                    acc[j][ot] = __builtin_amdgcn_mfma_f32_16x16x32_f16(aw0[ot], f0, acc[j][ot], 0, 0, 0);
#pragma unroll
                for (int ot = 0; ot < NOT; ot++)
                    acc[j][ot] = __builtin_amdgcn_mfma_f32_16x16x32_f16(aw1[ot], f1, acc[j][ot], 0, 0, 0);
            }
#pragma unroll
            for (int j = 0; j < NT; j++) offc[j] = offn[j];
        } else {
            half8v f0[NT], f1[NT];
#pragma unroll
            for (int j = 0; j < NT; j++)
                d_issue_conv(xq0, xq1, yt[j], xt[j], ki, kj, PAD, f0[j], f1[j]);
#pragma unroll
            for (int j = 0; j < NT; j++) {
#pragma unroll
                for (int ot = 0; ot < NOT; ot++)
                    acc[j][ot] = __builtin_amdgcn_mfma_f32_16x16x32_f16(aw0[ot], f0[j], acc[j][ot], 0, 0, 0);
#pragma unroll
                for (int ot = 0; ot < NOT; ot++)
                    acc[j][ot] = __builtin_amdgcn_mfma_f32_16x16x32_f16(aw1[ot], f1[j], acc[j][ot], 0, 0, 0);
            }
        }

        kj++;
        if (kj == K) { kj = 0; ki++; }
    }

    // ---- epilogue: D reg i -> o = ot*16 + q*4 + i, pos = gp[j] ----
    if (DEFORM) {
        _Float16* outp = (_Float16*)outv;
#pragma unroll
        for (int j = 0; j < NT; j++) {
            int hwp = hwb + (wave * NT + j) * 16 + p;
#pragma unroll
            for (int ot = 0; ot < NOT; ot++) {
                int ob = ot * 16 + q * 4;
                int plane = ob >> 3;
                int intra = ob & 7;
                float4 bb = *(const float4*)&bias[ob];
                half4v r;
                r[0] = (_Float16)(acc[j][ot][0] + bb.x);
                r[1] = (_Float16)(acc[j][ot][1] + bb.y);
                r[2] = (_Float16)(acc[j][ot][2] + bb.z);
                r[3] = (_Float16)(acc[j][ot][3] + bb.w);
                *(half4v*)&outp[(size_t)b * HW * 64 + (size_t)plane * HW * 8
                                + (size_t)hwp * 8 + intra] = r;
            }
        }
    } else {
        float* outf = (float*)outv;   // tap-major float2 planes
#pragma unroll
        for (int j = 0; j < NT; j++) {
#pragma unroll
            for (int ot = 0; ot < NOT; ot++) {
                int ob = ot * 16 + q * 4;     // channels ob..ob+3 = taps ob/2, ob/2+1
                int t0 = ob >> 1;
                if (t0 < KTAP) {
                    float2 r; r.x = acc[j][ot][0] + bias[ob];     r.y = acc[j][ot][1] + bias[ob + 1];
                    *(float2*)&outf[((size_t)t0 * NPOS + gp[j]) * 2] = r;
                }
                if (t0 + 1 < KTAP) {
                    float2 r; r.x = acc[j][ot][2] + bias[ob + 2]; r.y = acc[j][ot][3] + bias[ob + 3];
                    *(float2*)&outf[((size_t)(t0 + 1) * NPOS + gp[j]) * 2] = r;
                }
            }
        }
    }
}

// ---------------------------------------------------------------------------
// k_sconv v4: LDS-staged deform conv, v1 geometry (proven 260us for K=7):
// block = 16 rows x 8 cols of positions, 256 threads = 4 waves x NT=2 tiles
// (tile = 2rows x 8cols). Staged region (16+2H)x(8+2H) px, 128 B/px:
// 48 KB (K=7) / 38.5 KB (K=5) / 30 KB (K=3) -> 3-5 blocks/CU, grid 1152
// (4.5 rounds/CU, good tail amortization -- round-3's 512-thr/576-block
// variant had a 2.25-round grid and died on dispatch tails, 17.9% occ).
// NEW in v4: the 2-deep corner-fetch pipeline is ROTATED ACROSS TAPS:
//   ... fetch T1(k) | combine+MFMA T0(k) | fetch T0(k+1) | combine+MFMA T1(k) ...
// so every combine has a full ds_read batch outstanding (~150cy cover).
// v1/v3 issued fetch T0(k) right before combine T0(k) -> ~120cy ds latency
// exposed once per tap per wave. Register cost: zero (still 2 CornerRegs).
// Swizzle: v1's measured 16B-slot form, key = pix & 7 (write and read).
// Per-lane global fallback when a corner exits the halo (|off|>=1).
// Numerics identical (same fp16 samples/combine/MFMA order).
// ---------------------------------------------------------------------------
template<int K, int PAD, int HALO>
__global__ __launch_bounds__(256) void k_sconv(
    const _Float16* __restrict__ xin, const float* __restrict__ offp,
    const _Float16* __restrict__ wtb, const float* __restrict__ bias,
    _Float16* __restrict__ outp)
{
    constexpr int KK = K * K;
    constexpr int RB = 16 + 2 * HALO;     // staged rows
    constexpr int WB = 8  + 2 * HALO;     // staged cols
    constexpr int NT = 2;

    __shared__ half8v sm[RB * WB * 8];    // 16B slot per (pixel, plane)

    int bi  = blockIdx.x;
    int b   = bi / 288;                   // 288 = 12 row-tiles * 24 col-tiles
    int tt  = bi % 288;
    int by0 = (tt / 24) * 16;
    int bx0 = (tt % 24) * 8;
    int ry0 = by0 - HALO;
    int rx0 = bx0 - HALO;

    const _Float16* xb  = xin + (size_t)b * HW * 64;

    // ---- stage tile + halo (edge-clamped rows/cols) ----
    constexpr int CH = RB * WB * 8;       // 16B chunks
    for (int i = threadIdx.x; i < CH; i += 256) {
        int cc = i % WB;
        int rp = i / WB;
        int pl = rp & 7;
        int r  = rp >> 3;
        int yr = min(max(ry0 + r,  0), HH - 1);
        int xc = min(max(rx0 + cc, 0), WID - 1);
        half8v ch = *(const half8v*)(xb + ((size_t)pl * HW + (size_t)(yr * WID + xc)) * 8);
        int pix = r * WB + cc;
        sm[pix * 8 + (pl ^ (pix & 7))] = ch;
    }
    __syncthreads();

    int t    = threadIdx.x;
    int lane = t & 63;
    int wave = t >> 6;                    // 0..3
    int p    = lane & 15;
    int q    = lane >> 4;
    int wlane = p * 8 + q;
    int dr   = p >> 3;                    // tile-local row (0..1)
    int dc   = p & 7;                     // tile-local col (0..7)

    const _Float16* xq0 = xb + (size_t)q * HW * 8;        // fallback planes
    const _Float16* xq1 = xb + (size_t)(q + 4) * HW * 8;
    const half8v* wbase = (const half8v*)wtb;

    int yt[NT], xt[NT], gp[NT];
#pragma unroll
    for (int j = 0; j < NT; j++) {
        int ti = wave * NT + j;           // 0..7
        yt[j] = by0 + ti * 2 + dr;
        xt[j] = bx0 + dc;
        gp[j] = b * HW + yt[j] * WID + xt[j];
    }

    f32x4 acc[NT][4];
#pragma unroll
    for (int j = 0; j < NT; j++)
#pragma unroll
        for (int ot = 0; ot < 4; ot++) acc[j][ot] = (f32x4){0.f, 0.f, 0.f, 0.f};

    const float2* offj[NT];
    float2 offc[NT], offn[NT];
#pragma unroll
    for (int j = 0; j < NT; j++) {
        offj[j] = (const float2*)offp + gp[j];
        offc[j] = offj[j][0];
    }

    // corner fetch for one tile-tap (fast: swizzled LDS; rare fallback: global)
    auto fetch = [&](int jt, int ki, int kj, float2 off, CornerRegs& C) {
        float py = (float)(yt[jt] + ki - PAD) + off.x;
        float px = (float)(xt[jt] + kj - PAD) + off.y;
        float fy = floorf(py), fx = floorf(px);
        float wy = py - fy, wx = px - fx;
        int iy0 = (int)fy, ix0 = (int)fx;
        int iy1 = iy0 + 1, ix1 = ix0 + 1;
        float m00 = (iy0 >= 0 && iy0 < HH && ix0 >= 0 && ix0 < WID) ? 1.f : 0.f;
        float m01 = (iy0 >= 0 && iy0 < HH && ix1 >= 0 && ix1 < WID) ? 1.f : 0.f;
        float m10 = (iy1 >= 0 && iy1 < HH && ix0 >= 0 && ix0 < WID) ? 1.f : 0.f;
        float m11 = (iy1 >= 0 && iy1 < HH && ix1 >= 0 && ix1 < WID) ? 1.f : 0.f;
        C.w00 = (1.f - wy) * (1.f - wx) * m00;
        C.w01 = (1.f - wy) * wx * m01;
        C.w10 = wy * (1.f - wx) * m10;
        C.w11 = wy * wx * m11;
        bool fast = (iy0 >= ry0) && (iy1 <= ry0 + RB - 1) &&
                    (ix0 >= rx0) && (ix1 <= rx0 + WB - 1);
        if (__builtin_expect(fast, 1)) {
            int p00 = (iy0 - ry0) * WB + (ix0 - rx0);
            int p01 = p00 + 1, p10 = p00 + WB, p11 = p00 + WB + 1;
            C.r[0] = sm[p00 * 8 + ( q      ^ (p00 & 7))];
            C.r[1] = sm[p00 * 8 + ((q + 4) ^ (p00 & 7))];
            C.r[2] = sm[p01 * 8 + ( q      ^ (p01 & 7))];
            C.r[3] = sm[p01 * 8 + ((q + 4) ^ (p01 & 7))];
            C.r[4] = sm[p10 * 8 + ( q      ^ (p10 & 7))];
            C.r[5] = sm[p10 * 8 + ((q + 4) ^ (p10 & 7))];
            C.r[6] = sm[p11 * 8 + ( q      ^ (p11 & 7))];
            C.r[7] = sm[p11 * 8 + ((q + 4) ^ (p11 & 7))];
        } else {
            int cy0 = min(max(iy0, 0), HH - 1), cy1 = min(max(iy1, 0), HH - 1);
            int cx0 = min(max(ix0, 0), WID - 1), cx1 = min(max(ix1, 0), WID - 1);
            size_t i00 = (size_t)(cy0 * WID + cx0) * 8, i01 = (size_t)(cy0 * WID + cx1) * 8;
            size_t i10 = (size_t)(cy1 * WID + cx0) * 8, i11 = (size_t)(cy1 * WID + cx1) * 8;
            C.r[0] = *(const half8v*)(xq0 + i00);  C.r[1] = *(const half8v*)(xq1 + i00);
            C.r[2] = *(const half8v*)(xq0 + i01);  C.r[3] = *(const half8v*)(xq1 + i01);
            C.r[4] = *(const half8v*)(xq0 + i10);  C.r[5] = *(const half8v*)(xq1 + i10);
            C.r[6] = *(const half8v*)(xq0 + i11);  C.r[7] = *(const half8v*)(xq1 + i11);
        }
    };

    CornerRegs CC[2];
    // prologue: first tap's tile-0 fetch
    fetch(0, 0, 0, offc[0], CC[0]);

    int ki = 0, kj = 0;
    for (int k = 0; k < KK; k++) {
        // prefetch next tap's offsets (plane k+1 exists: buffer has 50 planes)
#pragma unroll
        for (int j = 0; j < NT; j++)
            offn[j] = offj[j][(size_t)(k + 1) * NPOS];

        const half8v* wp = wbase + (size_t)k * 64 * 8;   // OP = 64
        half8v aw0[4], aw1[4];
#pragma unroll
        for (int ot = 0; ot < 4; ot++) {
            aw0[ot] = wp[ot * 128 + wlane];
            aw1[ot] = wp[ot * 128 + wlane + 4];
        }

        int kj1 = (kj == K - 1) ? 0 : kj + 1;
        int ki1 = (kj == K - 1) ? ki + 1 : ki;

        // step A: issue tile-1 fetch of tap k; combine+MFMA tile-0 (in flight)
        fetch(1, ki, kj, offc[1], CC[1]);
        {
            half8v f0, f1;
            d_combine(CC[0], f0, f1);
#pragma unroll
            for (int ot = 0; ot < 4; ot++)
                acc[0][ot] = __builtin_amdgcn_mfma_f32_16x16x32_f16(aw0[ot], f0, acc[0][ot], 0, 0, 0);
#pragma unroll
            for (int ot = 0; ot < 4; ot++)
                acc[0][ot] = __builtin_amdgcn_mfma_f32_16x16x32_f16(aw1[ot], f1, acc[0][ot], 0, 0, 0);
        }
        // step B: issue tile-0 fetch of tap k+1; combine+MFMA tile-1
        if (k + 1 < KK)
            fetch(0, ki1, kj1, offn[0], CC[0]);
        {
            half8v f0, f1;
            d_combine(CC[1], f0, f1);
#pragma unroll
            for (int ot = 0; ot < 4; ot++)
                acc[1][ot] = __builtin_amdgcn_mfma_f32_16x16x32_f16(aw0[ot], f0, acc[1][ot], 0, 0, 0);
#pragma unroll
            for (int ot = 0; ot < 4; ot++)
                acc[1][ot] = __builtin_amdgcn_mfma_f32_16x16x32_f16(aw1[ot], f1, acc[1][ot], 0, 0, 0);
        }

        offc[0] = offn[0];
        offc[1] = offn[1];
        kj = kj1; ki = ki1;
    }

    // ---- epilogue: D reg i -> o = ot*16 + q*4 + i, pos = (yt[j], xt[j]) ----
#pragma unroll
    for (int j = 0; j < NT; j++) {
        int hwp = yt[j] * WID + xt[j];
#pragma unroll
        for (int ot = 0; ot < 4; ot++) {
            int ob = ot * 16 + q * 4;
            int plane = ob >> 3;
            int intra = ob & 7;
            float4 bb = *(const float4*)&bias[ob];
            half4v r;
            r[0] = (_Float16)(acc[j][ot][0] + bb.x);
            r[1] = (_Float16)(acc[j][ot][1] + bb.y);
            r[2] = (_Float16)(acc[j][ot][2] + bb.z);
            r[3] = (_Float16)(acc[j][ot][3] + bb.w);
            *(half4v*)&outp[(size_t)b * HW * 64 + (size_t)plane * HW * 8
                            + (size_t)hwp * 8 + intra] = r;
        }
    }
}

// ---------------------------------------------------------------------------
// K4: h = x1_final + x2 (plane fp16); out = h @ w_out^T + b_out + x (NCHW fp32)
// ---------------------------------------------------------------------------
__global__ __launch_bounds__(256) void k_merge_out(
    const _Float16* __restrict__ x1f, const _Float16* __restrict__ x2,
    const float* __restrict__ xin, const float* __restrict__ w_out,
    const float* __restrict__ b_out, float* __restrict__ out)
{
    int p  = blockIdx.x * 256 + threadIdx.x;
    int b  = p / HW;
    int hw = p % HW;

    const _Float16* a1 = x1f + (size_t)b * HW * 64 + (size_t)hw * 8;
    const _Float16* a2 = x2  + (size_t)b * HW * 64 + (size_t)hw * 8;
    float v[64];
#pragma unroll
    for (int pl = 0; pl < 8; pl++) {
        half8v u1 = *(const half8v*)&a1[(size_t)pl * HW * 8];
        half8v u2 = *(const half8v*)&a2[(size_t)pl * HW * 8];
#pragma unroll
        for (int j = 0; j < 8; j++)
            v[pl * 8 + j] = (float)u1[j] + (float)u2[j];
    }

    size_t base = (size_t)b * CB * HW + hw;
    for (int o = 0; o < 64; o++) {
        float a = b_out[o] + xin[base + (size_t)o * HW];
#pragma unroll
        for (int c = 0; c < 64; c++) a += v[c] * w_out[o * 64 + c];
        out[base + (size_t)o * HW] = a;
    }
}

// ---------------------------------------------------------------------------
// Launch. Workspace: x1a/x1b/x2 plane fp16 (18.9 MB each), off tap-major
// float2 planes (50 planes * NPOS * 8B = 59 MB), fp16 weights (~1.3 MB).
// ---------------------------------------------------------------------------
extern "C" void kernel_launch(void* const* d_in, const int* in_sizes, int n_in,
                              void* d_out, int out_size, void* d_ws, size_t ws_size,
                              hipStream_t stream)
{
    const float* x     = (const float*)d_in[0];
    const float* ln_w  = (const float*)d_in[1];
    const float* ln_b  = (const float*)d_in[2];
    const float* w_in  = (const float*)d_in[3];
    const float* b_in  = (const float*)d_in[4];
    const float* w_out = (const float*)d_in[5];
    const float* b_out = (const float*)d_in[6];
    const float* dw1   = (const float*)d_in[7];
    const float* db1   = (const float*)d_in[8];
    const float* dw2   = (const float*)d_in[9];
    const float* db2   = (const float*)d_in[10];
    const float* dw3   = (const float*)d_in[11];
    const float* db3   = (const float*)d_in[12];
    const float* ow1   = (const float*)d_in[13];
    const float* ob1   = (const float*)d_in[14];
    const float* ow2   = (const float*)d_in[15];
    const float* ob2   = (const float*)d_in[16];
    const float* ow3   = (const float*)d_in[17];
    const float* ob3   = (const float*)d_in[18];

    _Float16* x1a = (_Float16*)d_ws;
    _Float16* x1b = x1a + (size_t)NPOS * 64;
    _Float16* x2  = x1b + (size_t)NPOS * 64;
    float* off = (float*)(x2 + (size_t)NPOS * 64);
    _Float16* wtd1 = (_Float16*)(off + (size_t)NPOS * 100);
    _Float16* wtd2 = wtd1 + 49 * 64 * 64;
    _Float16* wtd3 = wtd2 + 25 * 64 * 64;
    _Float16* wto1 = wtd3 +  9 * 64 * 64;
    _Float16* wto2 = wto1 + 25 * 112 * 64;
    _Float16* wto3 = wto2 + 25 * 64 * 64;

    // weight prep (fp16, [tap][o][c])
    k_wth<49, 64,  64><<<784, 256, 0, stream>>>(dw1, wtd1);
    k_wth<25, 64,  64><<<400, 256, 0, stream>>>(dw2, wtd2);
    k_wth< 9, 64,  64><<<144, 256, 0, stream>>>(dw3, wtd3);
    k_wth<25, 98, 112><<<700, 256, 0, stream>>>(ow1, wto1);
    k_wth<25, 50,  64><<<400, 256, 0, stream>>>(ow2, wto2);
    k_wth< 9, 18,  32><<< 72, 256, 0, stream>>>(ow3, wto3);

    k_ln_conv_in<<<NPOS / 256, 256, 0, stream>>>(x, ln_w, ln_b, w_in, b_in, x1a, x2);

    // offset convs: proven barrier-free k_mconv (NT=2, 1152 blocks)
    // deform convs: LDS-staged k_sconv v4 (16x8 tiles, 1152 blocks, 256 thr,
    //               cross-tap rotated corner pipeline)
    // stage 1
    k_mconv<5, 2, 7, 98, 2, false><<<1152, 256, 0, stream>>>(x1a, off, wto1, ob1, off);
    k_sconv<7, 3, 4><<<1152, 256, 0, stream>>>(x1a, off, wtd1, db1, x1b);
    // stage 2
    k_mconv<5, 2, 4, 50, 2, false><<<1152, 256, 0, stream>>>(x1b, off, wto2, ob2, off);
    k_sconv<5, 2, 3><<<1152, 256, 0, stream>>>(x1b, off, wtd2, db2, x1a);
    // stage 3
    k_mconv<3, 1, 2, 18, 2, false><<<1152, 256, 0, stream>>>(x1a, off, wto3, ob3, off);
    k_sconv<3, 1, 2><<<1152, 256, 0, stream>>>(x1a, off, wtd3, db3, x1b);

    k_merge_out<<<NPOS / 256, 256, 0, stream>>>(x1b, x2, x, w_out, b_out, (float*)d_out);
}

// Round 5
// 1169.989 us; speedup vs baseline: 1.6013x; 1.0080x over previous
//
#include <hip/hip_runtime.h>

// Problem constants (B=4, C=64, H=W=192)
#define HH 192
#define WID 192
#define HW (HH*WID)          // 36864
#define CB 64
#define BB 4
#define NPOS (BB*HW)         // 147456

typedef __attribute__((ext_vector_type(8))) _Float16 half8v;
typedef __attribute__((ext_vector_type(4))) _Float16 half4v;
typedef __attribute__((ext_vector_type(8))) unsigned short ushort8;
typedef __attribute__((ext_vector_type(4))) float f32x4;

static __device__ inline half8v splat8(_Float16 x) {
    half8v v = {x, x, x, x, x, x, x, x};
    return v;
}

// x tensors: CHANNEL-PLANE fp16 layout x[b][plane=c>>3][hw][8ch] (16B/pos/plane).
// Offsets: TAP-MAJOR float2 planes off[k][global_pos][2] (NPOS float2 per plane).

// ---------------------------------------------------------------------------
// K1: LayerNorm over C + 1x1 conv C->2C; outputs x1/x2 in plane-fp16 layout.
// ---------------------------------------------------------------------------
__global__ __launch_bounds__(256) void k_ln_conv_in(
    const float* __restrict__ x, const float* __restrict__ g, const float* __restrict__ be,
    const float* __restrict__ w_in, const float* __restrict__ b_in,
    _Float16* __restrict__ x1, _Float16* __restrict__ x2)
{
    int p  = blockIdx.x * 256 + threadIdx.x;     // [0, NPOS)
    int b  = p / HW;
    int hw = p % HW;
    const float* xp = x + (size_t)b * CB * HW + hw;

    float v[64];
    float sum = 0.f, sumsq = 0.f;
#pragma unroll
    for (int c = 0; c < 64; c++) {
        float t = xp[c * HW];
        v[c] = t; sum += t; sumsq += t * t;
    }
    float mu  = sum * (1.f / 64.f);
    float var = sumsq * (1.f / 64.f) - mu * mu;
    float inv = rsqrtf(var + 1e-5f);
#pragma unroll
    for (int c = 0; c < 64; c++) v[c] = (v[c] - mu) * inv * g[c] + be[c];

    _Float16* o1 = x1 + (size_t)b * HW * 64 + (size_t)hw * 8;
    _Float16* o2 = x2 + (size_t)b * HW * 64 + (size_t)hw * 8;
    for (int pl = 0; pl < 8; pl++) {            // pl = channel plane (8 ch)
        half8v r1, r2;
#pragma unroll
        for (int j = 0; j < 8; j++) {
            int o = pl * 8 + j;
            float a1 = b_in[o];
            float a2 = b_in[o + 64];
#pragma unroll
            for (int c = 0; c < 64; c++) {
                a1 += v[c] * w_in[o * 64 + c];
                a2 += v[c] * w_in[(o + 64) * 64 + c];
            }
            r1[j] = (_Float16)a1;
            r2[j] = (_Float16)a2;
        }
        *(half8v*)&o1[(size_t)pl * HW * 8] = r1;
        *(half8v*)&o2[(size_t)pl * HW * 8] = r2;
    }
}

// ---------------------------------------------------------------------------
// Weight prep: w[o][c][ki][kj] fp32 (OIHW) -> wt[k][o][c] fp16, o padded to OP.
// ---------------------------------------------------------------------------
template<int KK, int CO, int OP>
__global__ void k_wth(const float* __restrict__ w, _Float16* __restrict__ wt)
{
    int idx = blockIdx.x * 256 + threadIdx.x;
    constexpr int TOT = KK * OP * 64;
    if (idx >= TOT) return;
    int k = idx / (OP * 64);
    int r = idx % (OP * 64);
    int o = r / 64;
    int c = r % 64;
    float v = (o < CO) ? w[((size_t)o * 64 + c) * KK + k] : 0.f;
    wt[idx] = (_Float16)v;
}

// ---------------------------------------------------------------------------
// Corner-register set for one in-flight deform tile-tap.
// ---------------------------------------------------------------------------
struct CornerRegs {
    half8v r[8];             // {00lo,00hi,01lo,01hi,10lo,10hi,11lo,11hi}
    float w00, w01, w10, w11;
};

static __device__ inline void d_issue(const _Float16* __restrict__ xq0,
                                      const _Float16* __restrict__ xq1,
                                      int y, int xg, int ki, int kj, int PAD,
                                      float2 off, CornerRegs& C)
{
    float py = (float)(y + ki - PAD) + off.x;
    float px = (float)(xg + kj - PAD) + off.y;
    float fy = floorf(py), fx = floorf(px);
    float wy = py - fy, wx = px - fx;
    int iy0 = (int)fy, ix0 = (int)fx;
    int iy1 = iy0 + 1, ix1 = ix0 + 1;
    float m00 = (iy0 >= 0 && iy0 < HH && ix0 >= 0 && ix0 < WID) ? 1.f : 0.f;
    float m01 = (iy0 >= 0 && iy0 < HH && ix1 >= 0 && ix1 < WID) ? 1.f : 0.f;
    float m10 = (iy1 >= 0 && iy1 < HH && ix0 >= 0 && ix0 < WID) ? 1.f : 0.f;
    float m11 = (iy1 >= 0 && iy1 < HH && ix1 >= 0 && ix1 < WID) ? 1.f : 0.f;
    int cy0 = min(max(iy0, 0), HH - 1), cy1 = min(max(iy1, 0), HH - 1);
    int cx0 = min(max(ix0, 0), WID - 1), cx1 = min(max(ix1, 0), WID - 1);
    size_t i00 = (size_t)(cy0 * WID + cx0) * 8, i01 = (size_t)(cy0 * WID + cx1) * 8;
    size_t i10 = (size_t)(cy1 * WID + cx0) * 8, i11 = (size_t)(cy1 * WID + cx1) * 8;
    C.r[0] = *(const half8v*)(xq0 + i00);  C.r[1] = *(const half8v*)(xq1 + i00);
    C.r[2] = *(const half8v*)(xq0 + i01);  C.r[3] = *(const half8v*)(xq1 + i01);
    C.r[4] = *(const half8v*)(xq0 + i10);  C.r[5] = *(const half8v*)(xq1 + i10);
    C.r[6] = *(const half8v*)(xq0 + i11);  C.r[7] = *(const half8v*)(xq1 + i11);
    C.w00 = (1.f - wy) * (1.f - wx) * m00;
    C.w01 = (1.f - wy) * wx * m01;
    C.w10 = wy * (1.f - wx) * m10;
    C.w11 = wy * wx * m11;
}

// packed fp16 bilinear combine: ~8 v_pk_fma_f16 per half8v
static __device__ inline void d_combine(const CornerRegs& C, half8v& f0, half8v& f1)
{
    half8v w00v = splat8((_Float16)C.w00);
    half8v w01v = splat8((_Float16)C.w01);
    half8v w10v = splat8((_Float16)C.w10);
    half8v w11v = splat8((_Float16)C.w11);
    f0 = C.r[0] * w00v + C.r[2] * w01v + C.r[4] * w10v + C.r[6] * w11v;
    f1 = C.r[1] * w00v + C.r[3] * w01v + C.r[5] * w10v + C.r[7] * w11v;
}

static __device__ inline void d_issue_conv(const _Float16* __restrict__ xq0,
                                           const _Float16* __restrict__ xq1,
                                           int y, int xg, int ki, int kj, int PAD,
                                           half8v& f0, half8v& f1)
{
    int gy = y + ki - PAD;
    int gx = xg + kj - PAD;
    bool ok = (gy >= 0 && gy < HH && gx >= 0 && gx < WID);
    if (ok) {
        size_t i = (size_t)(gy * WID + gx) * 8;
        f0 = *(const half8v*)(xq0 + i);
        f1 = *(const half8v*)(xq1 + i);
    } else {
        f0 = splat8((_Float16)0.f); f1 = splat8((_Float16)0.f);
    }
}

// ---------------------------------------------------------------------------
// Barrier-free wave-local MFMA conv, plane fp16 layout, NT pos-tiles per wave.
// (kept for the DEFORM=false offset convs; deform path uses k_sconv)
// ---------------------------------------------------------------------------
template<int K, int PAD, int NOT, int CO, int NT, bool DEFORM>
__global__ __launch_bounds__(256) void k_mconv(
    const _Float16* __restrict__ xin, const float* __restrict__ offp,
    const _Float16* __restrict__ wtb, const float* __restrict__ bias,
    void* __restrict__ outv)
{
    constexpr int KK = K * K;
    constexpr int OP = NOT * 16;
    constexpr int KTAP = CO / 2;                 // tap count of the offset consumer
    constexpr int BP = 64 * NT;                  // positions per block

    int p0  = blockIdx.x * BP;
    int b   = p0 / HW;
    int hwb = p0 % HW;

    int t    = threadIdx.x;
    int lane = t & 63;
    int wave = t >> 6;
    int p    = lane & 15;
    int q    = lane >> 4;
    int wlane = p * 8 + q;            // A-frag offset (half8 units)

    // per-tile coordinates
    int yt[NT], xt[NT], gp[NT];
#pragma unroll
    for (int j = 0; j < NT; j++) {
        int hwt = hwb + (wave * NT + j) * 16;
        yt[j] = hwt / WID;
        xt[j] = hwt % WID + p;
        gp[j] = p0 + (wave * NT + j) * 16 + p;
    }

    f32x4 acc[NT][NOT];
#pragma unroll
    for (int j = 0; j < NT; j++)
#pragma unroll
        for (int ot = 0; ot < NOT; ot++) acc[j][ot] = (f32x4){0.f, 0.f, 0.f, 0.f};

    const _Float16* xb  = xin + (size_t)b * HW * 64;
    const _Float16* xq0 = xb + (size_t)q * HW * 8;          // chunk-0 plane
    const _Float16* xq1 = xb + (size_t)(q + 4) * HW * 8;    // chunk-1 plane
    const half8v* wbase = (const half8v*)wtb;

    const float2* offj[NT];
    float2 offc[NT], offn[NT];
    if (DEFORM) {
#pragma unroll
        for (int j = 0; j < NT; j++) {
            offj[j] = (const float2*)offp + gp[j];
            offc[j] = offj[j][0];
        }
    }

    int ki = 0, kj = 0;
    for (int k = 0; k < KK; k++) {
        if (DEFORM) {
#pragma unroll
            for (int j = 0; j < NT; j++)
                offn[j] = offj[j][(size_t)(k + 1) * NPOS];
        }
        const half8v* wp = wbase + (size_t)k * OP * 8;
        half8v aw0[NOT], aw1[NOT];
#pragma unroll
        for (int ot = 0; ot < NOT; ot++) {
            aw0[ot] = wp[ot * 128 + wlane];
            aw1[ot] = wp[ot * 128 + wlane + 4];
        }

        if (DEFORM) {
            CornerRegs CC[2];
            d_issue(xq0, xq1, yt[0], xt[0], ki, kj, PAD, offc[0], CC[0]);
#pragma unroll
            for (int j = 0; j < NT; j++) {
                if (j + 1 < NT)
                    d_issue(xq0, xq1, yt[j + 1], xt[j + 1], ki, kj, PAD, offc[j + 1], CC[(j + 1) & 1]);
                half8v f0, f1;
                d_combine(CC[j & 1], f0, f1);
#pragma unroll
                for (int ot = 0; ot < NOT; ot++)
                    acc[j][ot] = __builtin_amdgcn_mfma_f32_16x16x32_f16(aw0[ot], f0, acc[j][ot], 0, 0, 0);
#pragma unroll
                for (int ot = 0; ot < NOT; ot++)
                    acc[j][ot] = __builtin_amdgcn_mfma_f32_16x16x32_f16(aw1[ot], f1, acc[j][ot], 0, 0, 0);
            }
#pragma unroll
            for (int j = 0; j < NT; j++) offc[j] = offn[j];
        } else {
            half8v f0[NT], f1[NT];
#pragma unroll
            for (int j = 0; j < NT; j++)
                d_issue_conv(xq0, xq1, yt[j], xt[j], ki, kj, PAD, f0[j], f1[j]);
#pragma unroll
            for (int j = 0; j < NT; j++) {
#pragma unroll
                for (int ot = 0; ot < NOT; ot++)
                    acc[j][ot] = __builtin_amdgcn_mfma_f32_16x16x32_f16(aw0[ot], f0[j], acc[j][ot], 0, 0, 0);
#pragma unroll
                for (int ot = 0; ot < NOT; ot++)
                    acc[j][ot] = __builtin_amdgcn_mfma_f32_16x16x32_f16(aw1[ot], f1[j], acc[j][ot], 0, 0, 0);
            }
        }

        kj++;
        if (kj == K) { kj = 0; ki++; }
    }

    // ---- epilogue: D reg i -> o = ot*16 + q*4 + i, pos = gp[j] ----
    if (DEFORM) {
        _Float16* outp = (_Float16*)outv;
#pragma unroll
        for (int j = 0; j < NT; j++) {
            int hwp = hwb + (wave * NT + j) * 16 + p;
#pragma unroll
            for (int ot = 0; ot < NOT; ot++) {
                int ob = ot * 16 + q * 4;
                int plane = ob >> 3;
                int intra = ob & 7;
                float4 bb = *(const float4*)&bias[ob];
                half4v r;
                r[0] = (_Float16)(acc[j][ot][0] + bb.x);
                r[1] = (_Float16)(acc[j][ot][1] + bb.y);
                r[2] = (_Float16)(acc[j][ot][2] + bb.z);
                r[3] = (_Float16)(acc[j][ot][3] + bb.w);
                *(half4v*)&outp[(size_t)b * HW * 64 + (size_t)plane * HW * 8
                                + (size_t)hwp * 8 + intra] = r;
            }
        }
    } else {
        float* outf = (float*)outv;   // tap-major float2 planes
#pragma unroll
        for (int j = 0; j < NT; j++) {
#pragma unroll
            for (int ot = 0; ot < NOT; ot++) {
                int ob = ot * 16 + q * 4;     // channels ob..ob+3 = taps ob/2, ob/2+1
                int t0 = ob >> 1;
                if (t0 < KTAP) {
                    float2 r; r.x = acc[j][ot][0] + bias[ob];     r.y = acc[j][ot][1] + bias[ob + 1];
                    *(float2*)&outf[((size_t)t0 * NPOS + gp[j]) * 2] = r;
                }
                if (t0 + 1 < KTAP) {
                    float2 r; r.x = acc[j][ot][2] + bias[ob + 2]; r.y = acc[j][ot][3] + bias[ob + 3];
                    *(float2*)&outf[((size_t)(t0 + 1) * NPOS + gp[j]) * 2] = r;
                }
            }
        }
    }
}

// ---------------------------------------------------------------------------
// k_sconv v5: LDS-staged deform conv, v1 geometry (16x8 tile, 256 thr,
// 4 waves x NT=2, 48/38.5/30 KB LDS, grid 1152) + cross-tap rotated corner
// pipeline (v4) + 2-TAP-DEEP OFFSET PIPELINE (new).
// LESSON (round 4): the rotated fetch consumed off[k+1] loaded in the SAME
// iteration -> exposed ~400-600cy global latency per tap (59MB offset buffer
// is L3-resident at best); dur regressed 260->308 despite the rotation.
// v5 keeps three offset register stages:
//   offA = off[k]   (step-A fetch; loaded 2 taps ago)
//   offB = off[k+1] (step-B rotated fetch; loaded 1 tap ago -- full cover)
//   offN = off[k+2] (issued this tap, plane clamped to KK-1 at tail)
// Steady state: NO load (global or LDS) is consumed in the phase it was
// issued. Weight prefetch deliberately not added (register-pressure risk).
// Swizzle: v1's measured 16B-slot form, key = pix & 7 (write and read).
// Per-lane global fallback when a corner exits the halo (|off|>=1).
// Numerics identical (same fp16 samples/combine/MFMA order).
// ---------------------------------------------------------------------------
template<int K, int PAD, int HALO>
__global__ __launch_bounds__(256) void k_sconv(
    const _Float16* __restrict__ xin, const float* __restrict__ offp,
    const _Float16* __restrict__ wtb, const float* __restrict__ bias,
    _Float16* __restrict__ outp)
{
    constexpr int KK = K * K;
    constexpr int RB = 16 + 2 * HALO;     // staged rows
    constexpr int WB = 8  + 2 * HALO;     // staged cols
    constexpr int NT = 2;

    __shared__ half8v sm[RB * WB * 8];    // 16B slot per (pixel, plane)

    int bi  = blockIdx.x;
    int b   = bi / 288;                   // 288 = 12 row-tiles * 24 col-tiles
    int tt  = bi % 288;
    int by0 = (tt / 24) * 16;
    int bx0 = (tt % 24) * 8;
    int ry0 = by0 - HALO;
    int rx0 = bx0 - HALO;

    const _Float16* xb  = xin + (size_t)b * HW * 64;

    // ---- stage tile + halo (edge-clamped rows/cols) ----
    constexpr int CH = RB * WB * 8;       // 16B chunks
    for (int i = threadIdx.x; i < CH; i += 256) {
        int cc = i % WB;
        int rp = i / WB;
        int pl = rp & 7;
        int r  = rp >> 3;
        int yr = min(max(ry0 + r,  0), HH - 1);
        int xc = min(max(rx0 + cc, 0), WID - 1);
        half8v ch = *(const half8v*)(xb + ((size_t)pl * HW + (size_t)(yr * WID + xc)) * 8);
        int pix = r * WB + cc;
        sm[pix * 8 + (pl ^ (pix & 7))] = ch;
    }
    __syncthreads();

    int t    = threadIdx.x;
    int lane = t & 63;
    int wave = t >> 6;                    // 0..3
    int p    = lane & 15;
    int q    = lane >> 4;
    int wlane = p * 8 + q;

    const _Float16* xq0 = xb + (size_t)q * HW * 8;        // fallback planes
    const _Float16* xq1 = xb + (size_t)(q + 4) * HW * 8;
    const half8v* wbase = (const half8v*)wtb;

    int dr   = p >> 3;                    // tile-local row (0..1)
    int dc   = p & 7;                     // tile-local col (0..7)

    int yt[NT], xt[NT], gp[NT];
#pragma unroll
    for (int j = 0; j < NT; j++) {
        int ti = wave * NT + j;           // 0..7
        yt[j] = by0 + ti * 2 + dr;
        xt[j] = bx0 + dc;
        gp[j] = b * HW + yt[j] * WID + xt[j];
    }

    f32x4 acc[NT][4];
#pragma unroll
    for (int j = 0; j < NT; j++)
#pragma unroll
        for (int ot = 0; ot < 4; ot++) acc[j][ot] = (f32x4){0.f, 0.f, 0.f, 0.f};

    const float2* offj[NT];
#pragma unroll
    for (int j = 0; j < NT; j++)
        offj[j] = (const float2*)offp + gp[j];

    // 3-stage offset pipeline: offA=off[k], offB=off[k+1], offN=off[k+2]
    float2 offA[NT], offB[NT], offN[NT];
#pragma unroll
    for (int j = 0; j < NT; j++) {
        offA[j] = offj[j][0];
        offB[j] = offj[j][NPOS];          // plane 1 (KK >= 9 always)
    }

    // corner fetch for one tile-tap (fast: swizzled LDS; rare fallback: global)
    auto fetch = [&](int jt, int ki, int kj, float2 off, CornerRegs& C) {
        float py = (float)(yt[jt] + ki - PAD) + off.x;
        float px = (float)(xt[jt] + kj - PAD) + off.y;
        float fy = floorf(py), fx = floorf(px);
        float wy = py - fy, wx = px - fx;
        int iy0 = (int)fy, ix0 = (int)fx;
        int iy1 = iy0 + 1, ix1 = ix0 + 1;
        float m00 = (iy0 >= 0 && iy0 < HH && ix0 >= 0 && ix0 < WID) ? 1.f : 0.f;
        float m01 = (iy0 >= 0 && iy0 < HH && ix1 >= 0 && ix1 < WID) ? 1.f : 0.f;
        float m10 = (iy1 >= 0 && iy1 < HH && ix0 >= 0 && ix0 < WID) ? 1.f : 0.f;
        float m11 = (iy1 >= 0 && iy1 < HH && ix1 >= 0 && ix1 < WID) ? 1.f : 0.f;
        C.w00 = (1.f - wy) * (1.f - wx) * m00;
        C.w01 = (1.f - wy) * wx * m01;
        C.w10 = wy * (1.f - wx) * m10;
        C.w11 = wy * wx * m11;
        bool fast = (iy0 >= ry0) && (iy1 <= ry0 + RB - 1) &&
                    (ix0 >= rx0) && (ix1 <= rx0 + WB - 1);
        if (__builtin_expect(fast, 1)) {
            int p00 = (iy0 - ry0) * WB + (ix0 - rx0);
            int p01 = p00 + 1, p10 = p00 + WB, p11 = p00 + WB + 1;
            C.r[0] = sm[p00 * 8 + ( q      ^ (p00 & 7))];
            C.r[1] = sm[p00 * 8 + ((q + 4) ^ (p00 & 7))];
            C.r[2] = sm[p01 * 8 + ( q      ^ (p01 & 7))];
            C.r[3] = sm[p01 * 8 + ((q + 4) ^ (p01 & 7))];
            C.r[4] = sm[p10 * 8 + ( q      ^ (p10 & 7))];
            C.r[5] = sm[p10 * 8 + ((q + 4) ^ (p10 & 7))];
            C.r[6] = sm[p11 * 8 + ( q      ^ (p11 & 7))];
            C.r[7] = sm[p11 * 8 + ((q + 4) ^ (p11 & 7))];
        } else {
            int cy0 = min(max(iy0, 0), HH - 1), cy1 = min(max(iy1, 0), HH - 1);
            int cx0 = min(max(ix0, 0), WID - 1), cx1 = min(max(ix1, 0), WID - 1);
            size_t i00 = (size_t)(cy0 * WID + cx0) * 8, i01 = (size_t)(cy0 * WID + cx1) * 8;
            size_t i10 = (size_t)(cy1 * WID + cx0) * 8, i11 = (size_t)(cy1 * WID + cx1) * 8;
            C.r[0] = *(const half8v*)(xq0 + i00);  C.r[1] = *(const half8v*)(xq1 + i00);
            C.r[2] = *(const half8v*)(xq0 + i01);  C.r[3] = *(const half8v*)(xq1 + i01);
            C.r[4] = *(const half8v*)(xq0 + i10);  C.r[5] = *(const half8v*)(xq1 + i10);
            C.r[6] = *(const half8v*)(xq0 + i11);  C.r[7] = *(const half8v*)(xq1 + i11);
        }
    };

    CornerRegs CC[2];
    // prologue: first tap's tile-0 fetch (uses offA = off[0])
    fetch(0, 0, 0, offA[0], CC[0]);

    int ki = 0, kj = 0;
    for (int k = 0; k < KK; k++) {
        // issue off[k+2] loads (used 2 taps later; plane clamped at tail,
        // values unused there since step-B fetch is guarded by k+1<KK)
        int kp2 = (k + 2 < KK) ? (k + 2) : (KK - 1);
#pragma unroll
        for (int j = 0; j < NT; j++)
            offN[j] = offj[j][(size_t)kp2 * NPOS];

        const half8v* wp = wbase + (size_t)k * 64 * 8;   // OP = 64
        half8v aw0[4], aw1[4];
#pragma unroll
        for (int ot = 0; ot < 4; ot++) {
            aw0[ot] = wp[ot * 128 + wlane];
            aw1[ot] = wp[ot * 128 + wlane + 4];
        }

        int kj1 = (kj == K - 1) ? 0 : kj + 1;
        int ki1 = (kj == K - 1) ? ki + 1 : ki;

        // step A: issue tile-1 fetch of tap k (offA, loaded >=2 taps ago);
        //         combine+MFMA tile-0 (ds_reads issued last step B)
        fetch(1, ki, kj, offA[1], CC[1]);
        {
            half8v f0, f1;
            d_combine(CC[0], f0, f1);
#pragma unroll
            for (int ot = 0; ot < 4; ot++)
                acc[0][ot] = __builtin_amdgcn_mfma_f32_16x16x32_f16(aw0[ot], f0, acc[0][ot], 0, 0, 0);
#pragma unroll
            for (int ot = 0; ot < 4; ot++)
                acc[0][ot] = __builtin_amdgcn_mfma_f32_16x16x32_f16(aw1[ot], f1, acc[0][ot], 0, 0, 0);
        }
        // step B: issue tile-0 fetch of tap k+1 (offB, loaded 1 tap ago);
        //         combine+MFMA tile-1 (ds_reads issued in step A)
        if (k + 1 < KK)
            fetch(0, ki1, kj1, offB[0], CC[0]);
        {
            half8v f0, f1;
            d_combine(CC[1], f0, f1);
#pragma unroll
            for (int ot = 0; ot < 4; ot++)
                acc[1][ot] = __builtin_amdgcn_mfma_f32_16x16x32_f16(aw0[ot], f0, acc[1][ot], 0, 0, 0);
#pragma unroll
            for (int ot = 0; ot < 4; ot++)
                acc[1][ot] = __builtin_amdgcn_mfma_f32_16x16x32_f16(aw1[ot], f1, acc[1][ot], 0, 0, 0);
        }

        // rotate offset pipeline
#pragma unroll
        for (int j = 0; j < NT; j++) {
            offA[j] = offB[j];
            offB[j] = offN[j];
        }
        kj = kj1; ki = ki1;
    }

    // ---- epilogue: D reg i -> o = ot*16 + q*4 + i, pos = (yt[j], xt[j]) ----
#pragma unroll
    for (int j = 0; j < NT; j++) {
        int hwp = yt[j] * WID + xt[j];
#pragma unroll
        for (int ot = 0; ot < 4; ot++) {
            int ob = ot * 16 + q * 4;
            int plane = ob >> 3;
            int intra = ob & 7;
            float4 bb = *(const float4*)&bias[ob];
            half4v r;
            r[0] = (_Float16)(acc[j][ot][0] + bb.x);
            r[1] = (_Float16)(acc[j][ot][1] + bb.y);
            r[2] = (_Float16)(acc[j][ot][2] + bb.z);
            r[3] = (_Float16)(acc[j][ot][3] + bb.w);
            *(half4v*)&outp[(size_t)b * HW * 64 + (size_t)plane * HW * 8
                            + (size_t)hwp * 8 + intra] = r;
        }
    }
}

// ---------------------------------------------------------------------------
// K4: h = x1_final + x2 (plane fp16); out = h @ w_out^T + b_out + x (NCHW fp32)
// ---------------------------------------------------------------------------
__global__ __launch_bounds__(256) void k_merge_out(
    const _Float16* __restrict__ x1f, const _Float16* __restrict__ x2,
    const float* __restrict__ xin, const float* __restrict__ w_out,
    const float* __restrict__ b_out, float* __restrict__ out)
{
    int p  = blockIdx.x * 256 + threadIdx.x;
    int b  = p / HW;
    int hw = p % HW;

    const _Float16* a1 = x1f + (size_t)b * HW * 64 + (size_t)hw * 8;
    const _Float16* a2 = x2  + (size_t)b * HW * 64 + (size_t)hw * 8;
    float v[64];
#pragma unroll
    for (int pl = 0; pl < 8; pl++) {
        half8v u1 = *(const half8v*)&a1[(size_t)pl * HW * 8];
        half8v u2 = *(const half8v*)&a2[(size_t)pl * HW * 8];
#pragma unroll
        for (int j = 0; j < 8; j++)
            v[pl * 8 + j] = (float)u1[j] + (float)u2[j];
    }

    size_t base = (size_t)b * CB * HW + hw;
    for (int o = 0; o < 64; o++) {
        float a = b_out[o] + xin[base + (size_t)o * HW];
#pragma unroll
        for (int c = 0; c < 64; c++) a += v[c] * w_out[o * 64 + c];
        out[base + (size_t)o * HW] = a;
    }
}

// ---------------------------------------------------------------------------
// Launch. Workspace: x1a/x1b/x2 plane fp16 (18.9 MB each), off tap-major
// float2 planes (50 planes * NPOS * 8B = 59 MB), fp16 weights (~1.3 MB).
// ---------------------------------------------------------------------------
extern "C" void kernel_launch(void* const* d_in, const int* in_sizes, int n_in,
                              void* d_out, int out_size, void* d_ws, size_t ws_size,
                              hipStream_t stream)
{
    const float* x     = (const float*)d_in[0];
    const float* ln_w  = (const float*)d_in[1];
    const float* ln_b  = (const float*)d_in[2];
    const float* w_in  = (const float*)d_in[3];
    const float* b_in  = (const float*)d_in[4];
    const float* w_out = (const float*)d_in[5];
    const float* b_out = (const float*)d_in[6];
    const float* dw1   = (const float*)d_in[7];
    const float* db1   = (const float*)d_in[8];
    const float* dw2   = (const float*)d_in[9];
    const float* db2   = (const float*)d_in[10];
    const float* dw3   = (const float*)d_in[11];
    const float* db3   = (const float*)d_in[12];
    const float* ow1   = (const float*)d_in[13];
    const float* ob1   = (const float*)d_in[14];
    const float* ow2   = (const float*)d_in[15];
    const float* ob2   = (const float*)d_in[16];
    const float* ow3   = (const float*)d_in[17];
    const float* ob3   = (const float*)d_in[18];

    _Float16* x1a = (_Float16*)d_ws;
    _Float16* x1b = x1a + (size_t)NPOS * 64;
    _Float16* x2  = x1b + (size_t)NPOS * 64;
    float* off = (float*)(x2 + (size_t)NPOS * 64);
    _Float16* wtd1 = (_Float16*)(off + (size_t)NPOS * 100);
    _Float16* wtd2 = wtd1 + 49 * 64 * 64;
    _Float16* wtd3 = wtd2 + 25 * 64 * 64;
    _Float16* wto1 = wtd3 +  9 * 64 * 64;
    _Float16* wto2 = wto1 + 25 * 112 * 64;
    _Float16* wto3 = wto2 + 25 * 64 * 64;

    // weight prep (fp16, [tap][o][c])
    k_wth<49, 64,  64><<<784, 256, 0, stream>>>(dw1, wtd1);
    k_wth<25, 64,  64><<<400, 256, 0, stream>>>(dw2, wtd2);
    k_wth< 9, 64,  64><<<144, 256, 0, stream>>>(dw3, wtd3);
    k_wth<25, 98, 112><<<700, 256, 0, stream>>>(ow1, wto1);
    k_wth<25, 50,  64><<<400, 256, 0, stream>>>(ow2, wto2);
    k_wth< 9, 18,  32><<< 72, 256, 0, stream>>>(ow3, wto3);

    k_ln_conv_in<<<NPOS / 256, 256, 0, stream>>>(x, ln_w, ln_b, w_in, b_in, x1a, x2);

    // offset convs: proven barrier-free k_mconv (NT=2, 1152 blocks)
    // deform convs: LDS-staged k_sconv v5 (16x8 tiles, 1152 blocks, 256 thr,
    //               rotated corner pipeline + 2-tap-deep offset pipeline)
    // stage 1
    k_mconv<5, 2, 7, 98, 2, false><<<1152, 256, 0, stream>>>(x1a, off, wto1, ob1, off);
    k_sconv<7, 3, 4><<<1152, 256, 0, stream>>>(x1a, off, wtd1, db1, x1b);
    // stage 2
    k_mconv<5, 2, 4, 50, 2, false><<<1152, 256, 0, stream>>>(x1b, off, wto2, ob2, off);
    k_sconv<5, 2, 3><<<1152, 256, 0, stream>>>(x1b, off, wtd2, db2, x1a);
    // stage 3
    k_mconv<3, 1, 2, 18, 2, false><<<1152, 256, 0, stream>>>(x1a, off, wto3, ob3, off);
    k_sconv<3, 1, 2><<<1152, 256, 0, stream>>>(x1a, off, wtd3, db3, x1b);

    k_merge_out<<<NPOS / 256, 256, 0, stream>>>(x1b, x2, x, w_out, b_out, (float*)d_out);
}

// Round 6
// 1091.832 us; speedup vs baseline: 1.7159x; 1.0716x over previous
//
#include <hip/hip_runtime.h>

// Problem constants (B=4, C=64, H=W=192)
#define HH 192
#define WID 192
#define HW (HH*WID)          // 36864
#define CB 64
#define BB 4
#define NPOS (BB*HW)         // 147456

typedef __attribute__((ext_vector_type(8))) _Float16 half8v;
typedef __attribute__((ext_vector_type(4))) _Float16 half4v;
typedef __attribute__((ext_vector_type(8))) unsigned short ushort8;
typedef __attribute__((ext_vector_type(4))) float f32x4;
typedef __attribute__((ext_vector_type(16))) float f32x16;

static __device__ inline half8v splat8(_Float16 x) {
    half8v v = {x, x, x, x, x, x, x, x};
    return v;
}

// x tensors: CHANNEL-PLANE fp16 layout x[b][plane=c>>3][hw][8ch] (16B/pos/plane).
// Offsets: TAP-MAJOR float2 planes off[k][global_pos][2] (NPOS float2 per plane).

// ---------------------------------------------------------------------------
// K1: LayerNorm over C + 1x1 conv C->2C; outputs x1/x2 in plane-fp16 layout.
// ---------------------------------------------------------------------------
__global__ __launch_bounds__(256) void k_ln_conv_in(
    const float* __restrict__ x, const float* __restrict__ g, const float* __restrict__ be,
    const float* __restrict__ w_in, const float* __restrict__ b_in,
    _Float16* __restrict__ x1, _Float16* __restrict__ x2)
{
    int p  = blockIdx.x * 256 + threadIdx.x;     // [0, NPOS)
    int b  = p / HW;
    int hw = p % HW;
    const float* xp = x + (size_t)b * CB * HW + hw;

    float v[64];
    float sum = 0.f, sumsq = 0.f;
#pragma unroll
    for (int c = 0; c < 64; c++) {
        float t = xp[c * HW];
        v[c] = t; sum += t; sumsq += t * t;
    }
    float mu  = sum * (1.f / 64.f);
    float var = sumsq * (1.f / 64.f) - mu * mu;
    float inv = rsqrtf(var + 1e-5f);
#pragma unroll
    for (int c = 0; c < 64; c++) v[c] = (v[c] - mu) * inv * g[c] + be[c];

    _Float16* o1 = x1 + (size_t)b * HW * 64 + (size_t)hw * 8;
    _Float16* o2 = x2 + (size_t)b * HW * 64 + (size_t)hw * 8;
    for (int pl = 0; pl < 8; pl++) {            // pl = channel plane (8 ch)
        half8v r1, r2;
#pragma unroll
        for (int j = 0; j < 8; j++) {
            int o = pl * 8 + j;
            float a1 = b_in[o];
            float a2 = b_in[o + 64];
#pragma unroll
            for (int c = 0; c < 64; c++) {
                a1 += v[c] * w_in[o * 64 + c];
                a2 += v[c] * w_in[(o + 64) * 64 + c];
            }
            r1[j] = (_Float16)a1;
            r2[j] = (_Float16)a2;
        }
        *(half8v*)&o1[(size_t)pl * HW * 8] = r1;
        *(half8v*)&o2[(size_t)pl * HW * 8] = r2;
    }
}

// ---------------------------------------------------------------------------
// Weight prep: w[o][c][ki][kj] fp32 (OIHW) -> wt[k][o][c] fp16, o padded to OP.
// ---------------------------------------------------------------------------
template<int KK, int CO, int OP>
__global__ void k_wth(const float* __restrict__ w, _Float16* __restrict__ wt)
{
    int idx = blockIdx.x * 256 + threadIdx.x;
    constexpr int TOT = KK * OP * 64;
    if (idx >= TOT) return;
    int k = idx / (OP * 64);
    int r = idx % (OP * 64);
    int o = r / 64;
    int c = r % 64;
    float v = (o < CO) ? w[((size_t)o * 64 + c) * KK + k] : 0.f;
    wt[idx] = (_Float16)v;
}

// ---------------------------------------------------------------------------
// Corner-register set for one in-flight deform tile-tap (k_mconv path).
// ---------------------------------------------------------------------------
struct CornerRegs {
    half8v r[8];             // {00lo,00hi,01lo,01hi,10lo,10hi,11lo,11hi}
    float w00, w01, w10, w11;
};

static __device__ inline void d_issue(const _Float16* __restrict__ xq0,
                                      const _Float16* __restrict__ xq1,
                                      int y, int xg, int ki, int kj, int PAD,
                                      float2 off, CornerRegs& C)
{
    float py = (float)(y + ki - PAD) + off.x;
    float px = (float)(xg + kj - PAD) + off.y;
    float fy = floorf(py), fx = floorf(px);
    float wy = py - fy, wx = px - fx;
    int iy0 = (int)fy, ix0 = (int)fx;
    int iy1 = iy0 + 1, ix1 = ix0 + 1;
    float m00 = (iy0 >= 0 && iy0 < HH && ix0 >= 0 && ix0 < WID) ? 1.f : 0.f;
    float m01 = (iy0 >= 0 && iy0 < HH && ix1 >= 0 && ix1 < WID) ? 1.f : 0.f;
    float m10 = (iy1 >= 0 && iy1 < HH && ix0 >= 0 && ix0 < WID) ? 1.f : 0.f;
    float m11 = (iy1 >= 0 && iy1 < HH && ix1 >= 0 && ix1 < WID) ? 1.f : 0.f;
    int cy0 = min(max(iy0, 0), HH - 1), cy1 = min(max(iy1, 0), HH - 1);
    int cx0 = min(max(ix0, 0), WID - 1), cx1 = min(max(ix1, 0), WID - 1);
    size_t i00 = (size_t)(cy0 * WID + cx0) * 8, i01 = (size_t)(cy0 * WID + cx1) * 8;
    size_t i10 = (size_t)(cy1 * WID + cx0) * 8, i11 = (size_t)(cy1 * WID + cx1) * 8;
    C.r[0] = *(const half8v*)(xq0 + i00);  C.r[1] = *(const half8v*)(xq1 + i00);
    C.r[2] = *(const half8v*)(xq0 + i01);  C.r[3] = *(const half8v*)(xq1 + i01);
    C.r[4] = *(const half8v*)(xq0 + i10);  C.r[5] = *(const half8v*)(xq1 + i10);
    C.r[6] = *(const half8v*)(xq0 + i11);  C.r[7] = *(const half8v*)(xq1 + i11);
    C.w00 = (1.f - wy) * (1.f - wx) * m00;
    C.w01 = (1.f - wy) * wx * m01;
    C.w10 = wy * (1.f - wx) * m10;
    C.w11 = wy * wx * m11;
}

// packed fp16 bilinear combine: ~8 v_pk_fma_f16 per half8v
static __device__ inline void d_combine(const CornerRegs& C, half8v& f0, half8v& f1)
{
    half8v w00v = splat8((_Float16)C.w00);
    half8v w01v = splat8((_Float16)C.w01);
    half8v w10v = splat8((_Float16)C.w10);
    half8v w11v = splat8((_Float16)C.w11);
    f0 = C.r[0] * w00v + C.r[2] * w01v + C.r[4] * w10v + C.r[6] * w11v;
    f1 = C.r[1] * w00v + C.r[3] * w01v + C.r[5] * w10v + C.r[7] * w11v;
}

static __device__ inline void d_issue_conv(const _Float16* __restrict__ xq0,
                                           const _Float16* __restrict__ xq1,
                                           int y, int xg, int ki, int kj, int PAD,
                                           half8v& f0, half8v& f1)
{
    int gy = y + ki - PAD;
    int gx = xg + kj - PAD;
    bool ok = (gy >= 0 && gy < HH && gx >= 0 && gx < WID);
    if (ok) {
        size_t i = (size_t)(gy * WID + gx) * 8;
        f0 = *(const half8v*)(xq0 + i);
        f1 = *(const half8v*)(xq1 + i);
    } else {
        f0 = splat8((_Float16)0.f); f1 = splat8((_Float16)0.f);
    }
}

// ---------------------------------------------------------------------------
// Barrier-free wave-local MFMA conv, plane fp16 layout, NT pos-tiles per wave.
// (kept for the DEFORM=false offset convs; deform path uses k_sconv)
// ---------------------------------------------------------------------------
template<int K, int PAD, int NOT, int CO, int NT, bool DEFORM>
__global__ __launch_bounds__(256) void k_mconv(
    const _Float16* __restrict__ xin, const float* __restrict__ offp,
    const _Float16* __restrict__ wtb, const float* __restrict__ bias,
    void* __restrict__ outv)
{
    constexpr int KK = K * K;
    constexpr int OP = NOT * 16;
    constexpr int KTAP = CO / 2;                 // tap count of the offset consumer
    constexpr int BP = 64 * NT;                  // positions per block

    int p0  = blockIdx.x * BP;
    int b   = p0 / HW;
    int hwb = p0 % HW;

    int t    = threadIdx.x;
    int lane = t & 63;
    int wave = t >> 6;
    int p    = lane & 15;
    int q    = lane >> 4;
    int wlane = p * 8 + q;            // A-frag offset (half8 units)

    // per-tile coordinates
    int yt[NT], xt[NT], gp[NT];
#pragma unroll
    for (int j = 0; j < NT; j++) {
        int hwt = hwb + (wave * NT + j) * 16;
        yt[j] = hwt / WID;
        xt[j] = hwt % WID + p;
        gp[j] = p0 + (wave * NT + j) * 16 + p;
    }

    f32x4 acc[NT][NOT];
#pragma unroll
    for (int j = 0; j < NT; j++)
#pragma unroll
        for (int ot = 0; ot < NOT; ot++) acc[j][ot] = (f32x4){0.f, 0.f, 0.f, 0.f};

    const _Float16* xb  = xin + (size_t)b * HW * 64;
    const _Float16* xq0 = xb + (size_t)q * HW * 8;          // chunk-0 plane
    const _Float16* xq1 = xb + (size_t)(q + 4) * HW * 8;    // chunk-1 plane
    const half8v* wbase = (const half8v*)wtb;

    const float2* offj[NT];
    float2 offc[NT], offn[NT];
    if (DEFORM) {
#pragma unroll
        for (int j = 0; j < NT; j++) {
            offj[j] = (const float2*)offp + gp[j];
            offc[j] = offj[j][0];
        }
    }

    int ki = 0, kj = 0;
    for (int k = 0; k < KK; k++) {
        if (DEFORM) {
#pragma unroll
            for (int j = 0; j < NT; j++)
                offn[j] = offj[j][(size_t)(k + 1) * NPOS];
        }
        const half8v* wp = wbase + (size_t)k * OP * 8;
        half8v aw0[NOT], aw1[NOT];
#pragma unroll
        for (int ot = 0; ot < NOT; ot++) {
            aw0[ot] = wp[ot * 128 + wlane];
            aw1[ot] = wp[ot * 128 + wlane + 4];
        }

        if (DEFORM) {
            CornerRegs CC[2];
            d_issue(xq0, xq1, yt[0], xt[0], ki, kj, PAD, offc[0], CC[0]);
#pragma unroll
            for (int j = 0; j < NT; j++) {
                if (j + 1 < NT)
                    d_issue(xq0, xq1, yt[j + 1], xt[j + 1], ki, kj, PAD, offc[j + 1], CC[(j + 1) & 1]);
                half8v f0, f1;
                d_combine(CC[j & 1], f0, f1);
#pragma unroll
                for (int ot = 0; ot < NOT; ot++)
                    acc[j][ot] = __builtin_amdgcn_mfma_f32_16x16x32_f16(aw0[ot], f0, acc[j][ot], 0, 0, 0);
#pragma unroll
                for (int ot = 0; ot < NOT; ot++)
                    acc[j][ot] = __builtin_amdgcn_mfma_f32_16x16x32_f16(aw1[ot], f1, acc[j][ot], 0, 0, 0);
            }
#pragma unroll
            for (int j = 0; j < NT; j++) offc[j] = offn[j];
        } else {
            half8v f0[NT], f1[NT];
#pragma unroll
            for (int j = 0; j < NT; j++)
                d_issue_conv(xq0, xq1, yt[j], xt[j], ki, kj, PAD, f0[j], f1[j]);
#pragma unroll
            for (int j = 0; j < NT; j++) {
#pragma unroll
                for (int ot = 0; ot < NOT; ot++)
                    acc[j][ot] = __builtin_amdgcn_mfma_f32_16x16x32_f16(aw0[ot], f0[j], acc[j][ot], 0, 0, 0);
#pragma unroll
                for (int ot = 0; ot < NOT; ot++)
                    acc[j][ot] = __builtin_amdgcn_mfma_f32_16x16x32_f16(aw1[ot], f1[j], acc[j][ot], 0, 0, 0);
            }
        }

        kj++;
        if (kj == K) { kj = 0; ki++; }
    }

    // ---- epilogue: D reg i -> o = ot*16 + q*4 + i, pos = gp[j] ----
    if (DEFORM) {
        _Float16* outp = (_Float16*)outv;
#pragma unroll
        for (int j = 0; j < NT; j++) {
            int hwp = hwb + (wave * NT + j) * 16 + p;
#pragma unroll
            for (int ot = 0; ot < NOT; ot++) {
                int ob = ot * 16 + q * 4;
                int plane = ob >> 3;
                int intra = ob & 7;
                float4 bb = *(const float4*)&bias[ob];
                half4v r;
                r[0] = (_Float16)(acc[j][ot][0] + bb.x);
                r[1] = (_Float16)(acc[j][ot][1] + bb.y);
                r[2] = (_Float16)(acc[j][ot][2] + bb.z);
                r[3] = (_Float16)(acc[j][ot][3] + bb.w);
                *(half4v*)&outp[(size_t)b * HW * 64 + (size_t)plane * HW * 8
                                + (size_t)hwp * 8 + intra] = r;
            }
        }
    } else {
        float* outf = (float*)outv;   // tap-major float2 planes
#pragma unroll
        for (int j = 0; j < NT; j++) {
#pragma unroll
            for (int ot = 0; ot < NOT; ot++) {
                int ob = ot * 16 + q * 4;     // channels ob..ob+3 = taps ob/2, ob/2+1
                int t0 = ob >> 1;
                if (t0 < KTAP) {
                    float2 r; r.x = acc[j][ot][0] + bias[ob];     r.y = acc[j][ot][1] + bias[ob + 1];
                    *(float2*)&outf[((size_t)t0 * NPOS + gp[j]) * 2] = r;
                }
                if (t0 + 1 < KTAP) {
                    float2 r; r.x = acc[j][ot][2] + bias[ob + 2]; r.y = acc[j][ot][3] + bias[ob + 3];
                    *(float2*)&outf[((size_t)(t0 + 1) * NPOS + gp[j]) * 2] = r;
                }
            }
        }
    }
}

// ---------------------------------------------------------------------------
// k_sconv v6: LDS-staged deform conv with 32x32x16 MFMA.
// Geometry = round-1 v1 (best measured): 16x8-position block, 256 thr,
// grid 1152, staged (16+2H)x(8+2H) px * 128B -> 48/38.5/30 KB LDS.
// LESSONS: (r2) no min-waves launch_bounds (spill); (r4/r5) no hand-rotated
// pipelines (loop-carried deps defeat compiler scheduling; v1's straight-line
// tap body + 1-tap offset prefetch is the best schedule found).
// NEW: wave = 32 positions (4 rows x 8 cols) x 64 out-ch via
// mfma_f32_32x32x16_f16 (D: col=lane&31 -> pos, row=(reg&3)+8*(reg>>2)+4*h;
// A/B: row/col=lane&31, k=h*8+j, h=lane>>5). Only 2 lanes per position
// (vs 4 with 16x16x32) -> per-position addr/bilinear VALU and offset loads
// HALVE. LDS traffic unchanged: 16 ds_read_b128/lane/tap, slot swizzle
// pix&7 keeps uniform 8-lanes-per-16B-slot distribution.
// Per-lane sample for K-step m: channels c = m*16 + h*8 + j -> chunk 2m+h.
// Numerics: same fp16 bilinear combine; fp32 accum order differs only in
// K-split granularity (16 vs 32) -- within tolerance.
// ---------------------------------------------------------------------------
template<int K, int PAD, int HALO>
__global__ __launch_bounds__(256) void k_sconv(
    const _Float16* __restrict__ xin, const float* __restrict__ offp,
    const _Float16* __restrict__ wtb, const float* __restrict__ bias,
    _Float16* __restrict__ outp)
{
    constexpr int KK = K * K;
    constexpr int RB = 16 + 2 * HALO;     // staged rows
    constexpr int WB = 8  + 2 * HALO;     // staged cols

    __shared__ half8v sm[RB * WB * 8];    // 16B slot per (pixel, plane)

    int bi  = blockIdx.x;
    int b   = bi / 288;                   // 288 = 12 row-tiles * 24 col-tiles
    int tt  = bi % 288;
    int by0 = (tt / 24) * 16;
    int bx0 = (tt % 24) * 8;
    int ry0 = by0 - HALO;
    int rx0 = bx0 - HALO;

    const _Float16* xb  = xin + (size_t)b * HW * 64;

    // ---- stage tile + halo (edge-clamped rows/cols) ----
    constexpr int CH = RB * WB * 8;       // 16B chunks
    for (int i = threadIdx.x; i < CH; i += 256) {
        int cc = i % WB;
        int rp = i / WB;
        int pl = rp & 7;
        int r  = rp >> 3;
        int yr = min(max(ry0 + r,  0), HH - 1);
        int xc = min(max(rx0 + cc, 0), WID - 1);
        half8v ch = *(const half8v*)(xb + ((size_t)pl * HW + (size_t)(yr * WID + xc)) * 8);
        int pix = r * WB + cc;
        sm[pix * 8 + (pl ^ (pix & 7))] = ch;
    }
    __syncthreads();

    int t    = threadIdx.x;
    int lane = t & 63;
    int wave = t >> 6;                    // 0..3 -> rows wave*4..wave*4+3
    int l31  = lane & 31;                 // position index within wave tile
    int h    = lane >> 5;                 // K-half (channel chunk parity)
    int prow = l31 >> 3;                  // 0..3
    int pcol = l31 & 7;                   // 0..7

    int yt = by0 + wave * 4 + prow;
    int xt = bx0 + pcol;
    int gp = b * HW + yt * WID + xt;

    const half8v* wbase = (const half8v*)wtb;

    f32x16 acc0 = {0.f,0.f,0.f,0.f,0.f,0.f,0.f,0.f,0.f,0.f,0.f,0.f,0.f,0.f,0.f,0.f};
    f32x16 acc1 = {0.f,0.f,0.f,0.f,0.f,0.f,0.f,0.f,0.f,0.f,0.f,0.f,0.f,0.f,0.f,0.f};

    const float2* offj = (const float2*)offp + gp;
    float2 offc = offj[0];

    int ki = 0, kj = 0;
    for (int k = 0; k < KK; k++) {
        // prefetch next tap's offset (one tap of cover, v1-proven)
        float2 offn = offj[(size_t)(k + 1) * NPOS];

        // A-frags: W[o][c], o = t*32 + l31, chunk = 2m + h
        const half8v* wp = wbase + (size_t)k * 64 * 8;   // OP = 64
        half8v a0[4], a1[4];
#pragma unroll
        for (int m = 0; m < 4; m++) {
            a0[m] = wp[(size_t)l31 * 8 + m * 2 + h];
            a1[m] = wp[(size_t)(32 + l31) * 8 + m * 2 + h];
        }

        // per-lane sample coordinates (ONE position per lane-pair)
        float py = (float)(yt + ki - PAD) + offc.x;
        float px = (float)(xt + kj - PAD) + offc.y;
        float fy = floorf(py), fx = floorf(px);
        float wy = py - fy, wx = px - fx;
        int iy0 = (int)fy, ix0 = (int)fx;
        int iy1 = iy0 + 1, ix1 = ix0 + 1;
        float m00 = (iy0 >= 0 && iy0 < HH && ix0 >= 0 && ix0 < WID) ? 1.f : 0.f;
        float m01 = (iy0 >= 0 && iy0 < HH && ix1 >= 0 && ix1 < WID) ? 1.f : 0.f;
        float m10 = (iy1 >= 0 && iy1 < HH && ix0 >= 0 && ix0 < WID) ? 1.f : 0.f;
        float m11 = (iy1 >= 0 && iy1 < HH && ix1 >= 0 && ix1 < WID) ? 1.f : 0.f;
        half8v w00v = splat8((_Float16)((1.f - wy) * (1.f - wx) * m00));
        half8v w01v = splat8((_Float16)((1.f - wy) * wx * m01));
        half8v w10v = splat8((_Float16)(wy * (1.f - wx) * m10));
        half8v w11v = splat8((_Float16)(wy * wx * m11));

        bool fast = (iy0 >= ry0) && (iy1 <= ry0 + RB - 1) &&
                    (ix0 >= rx0) && (ix1 <= rx0 + WB - 1);

        if (__builtin_expect(fast, 1)) {
            int p00 = (iy0 - ry0) * WB + (ix0 - rx0);
            int p01 = p00 + 1, p10 = p00 + WB, p11 = p00 + WB + 1;
            int s00 = p00 & 7, s01 = p01 & 7, s10 = p10 & 7, s11 = p11 & 7;
#pragma unroll
            for (int m = 0; m < 4; m++) {
                int cs = m * 2 + h;
                half8v c00 = sm[p00 * 8 + (cs ^ s00)];
                half8v c01 = sm[p01 * 8 + (cs ^ s01)];
                half8v c10 = sm[p10 * 8 + (cs ^ s10)];
                half8v c11 = sm[p11 * 8 + (cs ^ s11)];
                half8v bf = c00 * w00v + c01 * w01v + c10 * w10v + c11 * w11v;
                acc0 = __builtin_amdgcn_mfma_f32_32x32x16_f16(a0[m], bf, acc0, 0, 0, 0);
                acc1 = __builtin_amdgcn_mfma_f32_32x32x16_f16(a1[m], bf, acc1, 0, 0, 0);
            }
        } else {
            int cy0 = min(max(iy0, 0), HH - 1), cy1 = min(max(iy1, 0), HH - 1);
            int cx0 = min(max(ix0, 0), WID - 1), cx1 = min(max(ix1, 0), WID - 1);
            size_t i00 = (size_t)(cy0 * WID + cx0) * 8, i01 = (size_t)(cy0 * WID + cx1) * 8;
            size_t i10 = (size_t)(cy1 * WID + cx0) * 8, i11 = (size_t)(cy1 * WID + cx1) * 8;
#pragma unroll
            for (int m = 0; m < 4; m++) {
                const _Float16* xq = xb + (size_t)(m * 2 + h) * HW * 8;
                half8v c00 = *(const half8v*)(xq + i00);
                half8v c01 = *(const half8v*)(xq + i01);
                half8v c10 = *(const half8v*)(xq + i10);
                half8v c11 = *(const half8v*)(xq + i11);
                half8v bf = c00 * w00v + c01 * w01v + c10 * w10v + c11 * w11v;
                acc0 = __builtin_amdgcn_mfma_f32_32x32x16_f16(a0[m], bf, acc0, 0, 0, 0);
                acc1 = __builtin_amdgcn_mfma_f32_32x32x16_f16(a1[m], bf, acc1, 0, 0, 0);
            }
        }

        offc = offn;
        kj++;
        if (kj == K) { kj = 0; ki++; }
    }

    // ---- epilogue: D: pos = l31, o = t*32 + (reg&3) + 8*(reg>>2) + 4*h ----
    int hwp = yt * WID + xt;
    _Float16* ob = outp + (size_t)b * HW * 64 + (size_t)hwp * 8 + 4 * h;
#pragma unroll
    for (int g = 0; g < 4; g++) {
        // tile 0: o = g*8 + 4h + i, plane = g
        float4 bb0 = *(const float4*)&bias[g * 8 + 4 * h];
        half4v r0;
        r0[0] = (_Float16)(acc0[g * 4 + 0] + bb0.x);
        r0[1] = (_Float16)(acc0[g * 4 + 1] + bb0.y);
        r0[2] = (_Float16)(acc0[g * 4 + 2] + bb0.z);
        r0[3] = (_Float16)(acc0[g * 4 + 3] + bb0.w);
        *(half4v*)&ob[(size_t)g * HW * 8] = r0;
        // tile 1: o = 32 + g*8 + 4h + i, plane = 4 + g
        float4 bb1 = *(const float4*)&bias[32 + g * 8 + 4 * h];
        half4v r1;
        r1[0] = (_Float16)(acc1[g * 4 + 0] + bb1.x);
        r1[1] = (_Float16)(acc1[g * 4 + 1] + bb1.y);
        r1[2] = (_Float16)(acc1[g * 4 + 2] + bb1.z);
        r1[3] = (_Float16)(acc1[g * 4 + 3] + bb1.w);
        *(half4v*)&ob[(size_t)(4 + g) * HW * 8] = r1;
    }
}

// ---------------------------------------------------------------------------
// K4: h = x1_final + x2 (plane fp16); out = h @ w_out^T + b_out + x (NCHW fp32)
// ---------------------------------------------------------------------------
__global__ __launch_bounds__(256) void k_merge_out(
    const _Float16* __restrict__ x1f, const _Float16* __restrict__ x2,
    const float* __restrict__ xin, const float* __restrict__ w_out,
    const float* __restrict__ b_out, float* __restrict__ out)
{
    int p  = blockIdx.x * 256 + threadIdx.x;
    int b  = p / HW;
    int hw = p % HW;

    const _Float16* a1 = x1f + (size_t)b * HW * 64 + (size_t)hw * 8;
    const _Float16* a2 = x2  + (size_t)b * HW * 64 + (size_t)hw * 8;
    float v[64];
#pragma unroll
    for (int pl = 0; pl < 8; pl++) {
        half8v u1 = *(const half8v*)&a1[(size_t)pl * HW * 8];
        half8v u2 = *(const half8v*)&a2[(size_t)pl * HW * 8];
#pragma unroll
        for (int j = 0; j < 8; j++)
            v[pl * 8 + j] = (float)u1[j] + (float)u2[j];
    }

    size_t base = (size_t)b * CB * HW + hw;
    for (int o = 0; o < 64; o++) {
        float a = b_out[o] + xin[base + (size_t)o * HW];
#pragma unroll
        for (int c = 0; c < 64; c++) a += v[c] * w_out[o * 64 + c];
        out[base + (size_t)o * HW] = a;
    }
}

// ---------------------------------------------------------------------------
// Launch. Workspace: x1a/x1b/x2 plane fp16 (18.9 MB each), off tap-major
// float2 planes (50 planes * NPOS * 8B = 59 MB), fp16 weights (~1.3 MB).
// ---------------------------------------------------------------------------
extern "C" void kernel_launch(void* const* d_in, const int* in_sizes, int n_in,
                              void* d_out, int out_size, void* d_ws, size_t ws_size,
                              hipStream_t stream)
{
    const float* x     = (const float*)d_in[0];
    const float* ln_w  = (const float*)d_in[1];
    const float* ln_b  = (const float*)d_in[2];
    const float* w_in  = (const float*)d_in[3];
    const float* b_in  = (const float*)d_in[4];
    const float* w_out = (const float*)d_in[5];
    const float* b_out = (const float*)d_in[6];
    const float* dw1   = (const float*)d_in[7];
    const float* db1   = (const float*)d_in[8];
    const float* dw2   = (const float*)d_in[9];
    const float* db2   = (const float*)d_in[10];
    const float* dw3   = (const float*)d_in[11];
    const float* db3   = (const float*)d_in[12];
    const float* ow1   = (const float*)d_in[13];
    const float* ob1   = (const float*)d_in[14];
    const float* ow2   = (const float*)d_in[15];
    const float* ob2   = (const float*)d_in[16];
    const float* ow3   = (const float*)d_in[17];
    const float* ob3   = (const float*)d_in[18];

    _Float16* x1a = (_Float16*)d_ws;
    _Float16* x1b = x1a + (size_t)NPOS * 64;
    _Float16* x2  = x1b + (size_t)NPOS * 64;
    float* off = (float*)(x2 + (size_t)NPOS * 64);
    _Float16* wtd1 = (_Float16*)(off + (size_t)NPOS * 100);
    _Float16* wtd2 = wtd1 + 49 * 64 * 64;
    _Float16* wtd3 = wtd2 + 25 * 64 * 64;
    _Float16* wto1 = wtd3 +  9 * 64 * 64;
    _Float16* wto2 = wto1 + 25 * 112 * 64;
    _Float16* wto3 = wto2 + 25 * 64 * 64;

    // weight prep (fp16, [tap][o][c])
    k_wth<49, 64,  64><<<784, 256, 0, stream>>>(dw1, wtd1);
    k_wth<25, 64,  64><<<400, 256, 0, stream>>>(dw2, wtd2);
    k_wth< 9, 64,  64><<<144, 256, 0, stream>>>(dw3, wtd3);
    k_wth<25, 98, 112><<<700, 256, 0, stream>>>(ow1, wto1);
    k_wth<25, 50,  64><<<400, 256, 0, stream>>>(ow2, wto2);
    k_wth< 9, 18,  32><<< 72, 256, 0, stream>>>(ow3, wto3);

    k_ln_conv_in<<<NPOS / 256, 256, 0, stream>>>(x, ln_w, ln_b, w_in, b_in, x1a, x2);

    // offset convs: proven barrier-free k_mconv (NT=2, 1152 blocks)
    // deform convs: LDS-staged k_sconv v6 (16x8 tiles, 1152 blocks, 256 thr,
    //               32x32x16 MFMA, 2 lanes/position)
    // stage 1
    k_mconv<5, 2, 7, 98, 2, false><<<1152, 256, 0, stream>>>(x1a, off, wto1, ob1, off);
    k_sconv<7, 3, 4><<<1152, 256, 0, stream>>>(x1a, off, wtd1, db1, x1b);
    // stage 2
    k_mconv<5, 2, 4, 50, 2, false><<<1152, 256, 0, stream>>>(x1b, off, wto2, ob2, off);
    k_sconv<5, 2, 3><<<1152, 256, 0, stream>>>(x1b, off, wtd2, db2, x1a);
    // stage 3
    k_mconv<3, 1, 2, 18, 2, false><<<1152, 256, 0, stream>>>(x1a, off, wto3, ob3, off);
    k_sconv<3, 1, 2><<<1152, 256, 0, stream>>>(x1a, off, wtd3, db3, x1b);

    k_merge_out<<<NPOS / 256, 256, 0, stream>>>(x1b, x2, x, w_out, b_out, (float*)d_out);
}